// Round 1
// baseline (988.820 us; speedup 1.0000x reference)
//
#include <hip/hip_runtime.h>

#define B_    8192
#define N_    29
#define F_    147
#define DC    429
#define KPAD  448
#define D_    128
#define ROWS  (B_*N_)          /* 237568 */
#define EPSBN 1e-5f
#define SLOTS 32

/* ws layout in floats */
#define U_OFF    0
#define X3_OFF   (ROWS*D_)                 /* 30408704 */
#define ACC_OFF  (X3_OFF + B_*D_)          /* 31457280 */
#define BN1_OFF  (ACC_OFF)                 /* 32*29*2 = 1856 */
#define BN2_OFF  (ACC_OFF + 1856)
#define BN3_OFF  (ACC_OFF + 3712)          /* 32*128*2 = 8192 */
#define FIN_OFF  (ACC_OFF + 11904)
#define M1_OFF   (FIN_OFF + 0)
#define IS1_OFF  (FIN_OFF + 32)
#define M2_OFF   (FIN_OFF + 64)
#define IS2_OFF  (FIN_OFF + 96)
#define M3_OFF   (FIN_OFF + 128)
#define IS3_OFF  (FIN_OFF + 256)
#define CSW_OFF  (FIN_OFF + 384)
#define V_OFF    (FIN_OFF + 512)

typedef __bf16 bf16x8 __attribute__((ext_vector_type(8)));
typedef float  f32x4  __attribute__((ext_vector_type(4)));

__device__ __forceinline__ unsigned short f2bf(float f) {
  unsigned int u = __float_as_uint(f);
  u += 0x7fffu + ((u >> 16) & 1u);
  return (unsigned short)(u >> 16);
}

#define TSTR 456   /* 448 + 8 pad: row stride 912 B -> 4-bank rotation per row */
#define WSTR 72    /* 64 + 8 pad */

/* K1: conv(k=3,5,7) + prelu -> t (bf16, LDS only) ; bn1 stats ; U = t @ Wg via MFMA */
__global__ __launch_bounds__(256, 2) void k1_conv_gemm(
    const float* __restrict__ X, const float* __restrict__ Wg,
    const float* __restrict__ wc1, const float* __restrict__ bc1,
    const float* __restrict__ wc2, const float* __restrict__ bc2,
    const float* __restrict__ wc3, const float* __restrict__ bc3,
    const float* __restrict__ acnn, float* __restrict__ ws)
{
  __shared__ unsigned short t_s[64*TSTR];
  __shared__ unsigned short wg_s[128*WSTR];
  __shared__ float st1[29], st2[29];

  const int tid  = threadIdx.x;
  const int row0 = blockIdx.x * 64;

  if (tid < 29) { st1[tid] = 0.f; st2[tid] = 0.f; }
  __syncthreads();

  /* ---- phase A: conv + prelu into t_s, fp32 stats ---- */
  {
    const int r = tid >> 2, q = tid & 3;
    const int row = row0 + r;
    const float* xr = X + (size_t)row * F_;
    const float w10 = wc1[0], w11 = wc1[1], w12 = wc1[2], b1 = bc1[0];
    const float w20 = wc2[0], w21 = wc2[1], w22 = wc2[2], w23 = wc2[3], w24 = wc2[4], b2 = bc2[0];
    const float w30 = wc3[0], w31 = wc3[1], w32 = wc3[2], w33 = wc3[3], w34 = wc3[4],
                w35 = wc3[5], w36 = wc3[6], b3 = bc3[0];
    const float ap = acnn[0];
    float s1 = 0.f, s2 = 0.f;
    for (int d = q; d < DC; d += 4) {
      float v;
      if (d < 145) {
        v = xr[d]*w10 + xr[d+1]*w11 + xr[d+2]*w12 + b1;
      } else if (d < 288) {
        const float* xf = xr + (d - 145);
        v = xf[0]*w20 + xf[1]*w21 + xf[2]*w22 + xf[3]*w23 + xf[4]*w24 + b2;
      } else {
        const float* xf = xr + (d - 288);
        v = xf[0]*w30 + xf[1]*w31 + xf[2]*w32 + xf[3]*w33 + xf[4]*w34 + xf[5]*w35 + xf[6]*w36 + b3;
      }
      v = (v >= 0.f) ? v : ap * v;
      s1 += v; s2 += v * v;
      t_s[r*TSTR + d] = f2bf(v);
    }
    for (int d = DC + q; d < KPAD; d += 4) t_s[r*TSTR + d] = 0;
    const int m = row % 29;
    atomicAdd(&st1[m], s1);
    atomicAdd(&st2[m], s2);
  }
  __syncthreads();
  if (tid < 29) {
    float* bn1 = ws + BN1_OFF + (size_t)(blockIdx.x & (SLOTS-1)) * 58;
    atomicAdd(&bn1[tid*2+0], st1[tid]);
    atomicAdd(&bn1[tid*2+1], st2[tid]);
  }

  /* ---- phase B: U = t @ Wg, MFMA 16x16x32 bf16 ---- */
  const int wv = tid >> 6, lane = tid & 63;
  const int lrow = lane & 15, quad = lane >> 4;
  const int rbase = (wv & 1) * 32, cbase = (wv >> 1) * 64;
  f32x4 acc[2][4];
  #pragma unroll
  for (int rt = 0; rt < 2; ++rt)
    #pragma unroll
    for (int nt = 0; nt < 4; ++nt)
      acc[rt][nt] = (f32x4){0.f, 0.f, 0.f, 0.f};

  for (int ks = 0; ks < 7; ++ks) {
    __syncthreads();
    for (int i = tid; i < 64*128; i += 256) {
      int dd = i >> 7, k = i & 127;
      int d = ks*64 + dd;
      float w = (d < DC) ? Wg[d*D_ + k] : 0.f;
      wg_s[k*WSTR + dd] = f2bf(w);
    }
    __syncthreads();
    #pragma unroll
    for (int kk = 0; kk < 2; ++kk) {
      bf16x8 afr0 = *(const bf16x8*)&t_s[(rbase      + lrow)*TSTR + ks*64 + kk*32 + quad*8];
      bf16x8 afr1 = *(const bf16x8*)&t_s[(rbase + 16 + lrow)*TSTR + ks*64 + kk*32 + quad*8];
      #pragma unroll
      for (int nt = 0; nt < 4; ++nt) {
        bf16x8 bfr = *(const bf16x8*)&wg_s[(cbase + nt*16 + lrow)*WSTR + kk*32 + quad*8];
        acc[0][nt] = __builtin_amdgcn_mfma_f32_16x16x32_bf16(afr0, bfr, acc[0][nt], 0, 0, 0);
        acc[1][nt] = __builtin_amdgcn_mfma_f32_16x16x32_bf16(afr1, bfr, acc[1][nt], 0, 0, 0);
      }
    }
  }

  float* U = ws + U_OFF;
  #pragma unroll
  for (int rt = 0; rt < 2; ++rt)
    #pragma unroll
    for (int nt = 0; nt < 4; ++nt)
      #pragma unroll
      for (int i = 0; i < 4; ++i) {
        int r = row0 + rbase + rt*16 + quad*4 + i;
        int c = cbase + nt*16 + lrow;
        U[(size_t)r * D_ + c] = acc[rt][nt][i];
      }
}

/* K2: finalize bn1; colsum(Wg); v = sum_h head_w[h]*normalize(centroids[h]) */
__global__ void k2_finalize1(const float* __restrict__ Wg,
                             const float* __restrict__ cent,
                             const float* __restrict__ hw,
                             float* __restrict__ ws)
{
  __shared__ float red[2];
  const int k = threadIdx.x; /* 128 */
  if (k < 29) {
    float s1 = 0.f, s2 = 0.f;
    for (int s = 0; s < SLOTS; ++s) {
      s1 += ws[BN1_OFF + s*58 + k*2 + 0];
      s2 += ws[BN1_OFF + s*58 + k*2 + 1];
    }
    const float inv = 1.f / (float)(B_ * DC);
    float mean = s1 * inv;
    float var  = s2 * inv - mean * mean;
    ws[M1_OFF  + k] = mean;
    ws[IS1_OFF + k] = rsqrtf(var + EPSBN);
  }
  float cs = 0.f;
  for (int d = 0; d < DC; ++d) cs += Wg[d*D_ + k];
  ws[CSW_OFF + k] = cs;

  float vk = 0.f;
  for (int h = 0; h < 4; ++h) {
    float c = cent[h*D_ + k];
    float ss = c * c;
    #pragma unroll
    for (int off = 32; off >= 1; off >>= 1) ss += __shfl_down(ss, off);
    if ((k & 63) == 0) red[k >> 6] = ss;
    __syncthreads();
    float nrm = sqrtf(red[0] + red[1]);
    vk += hw[h] * c / (nrm + 1e-8f);
    __syncthreads();
  }
  ws[V_OFF + k] = vk;
}

/* K3: y1 = prelu(corr @ bn1(t) @ Wg + bg) in 128-dim via U; bn2 stats; in-place over U */
__global__ __launch_bounds__(256) void k3_gnn(
    const float* __restrict__ corr, const float* __restrict__ bg,
    const float* __restrict__ agnn, float* __restrict__ ws)
{
  __shared__ float cw_s[29*29];
  __shared__ float U_s[29*128];
  __shared__ float part_s[2*29*128];
  __shared__ float cs_s[128], bg_s[128];
  __shared__ float m1_s[29], is1_s[29], cm_s[29], st1_s[29], st2_s[29];

  const int b = blockIdx.x, tid = threadIdx.x;
  const float* cb = corr + (size_t)b * 841;
  float* Ug = ws + U_OFF + (size_t)b * 3712;

  if (tid < 29) { st1_s[tid] = 0.f; st2_s[tid] = 0.f; }
  if (tid < 128) { cs_s[tid] = ws[CSW_OFF + tid]; bg_s[tid] = bg[tid]; }
  if (tid >= 128 && tid < 157) {
    m1_s[tid-128]  = ws[M1_OFF  + tid-128];
    is1_s[tid-128] = ws[IS1_OFF + tid-128];
  }
  for (int i = tid; i < 841; i += 256)  cw_s[i] = cb[i];
  for (int i = tid; i < 3712; i += 256) U_s[i]  = Ug[i];
  __syncthreads();
  for (int i = tid; i < 841; i += 256)  cw_s[i] *= is1_s[i % 29];
  __syncthreads();
  if (tid < 29) {
    float cm = 0.f;
    for (int m = 0; m < 29; ++m) cm += cw_s[tid*29 + m] * m1_s[m];
    cm_s[tid] = cm;
  }
  /* partial products: thread (k, half) covers m-range, all n */
  {
    const int k = tid & 127, half = tid >> 7;
    const int mlo = half ? 15 : 0, mhi = half ? 29 : 15;
    float accv[29];
    #pragma unroll
    for (int n = 0; n < 29; ++n) accv[n] = 0.f;
    for (int m = mlo; m < mhi; ++m) {
      float u = U_s[m*128 + k];
      #pragma unroll
      for (int n = 0; n < 29; ++n) accv[n] += cw_s[n*29 + m] * u;
    }
    float* pp = part_s + half*3712 + k;
    #pragma unroll
    for (int n = 0; n < 29; ++n) pp[n*128] = accv[n];
  }
  __syncthreads();
  const float ag = agnn[0];
  for (int idx = tid; idx < 3712; idx += 256) {
    int n = idx >> 7, k = idx & 127;
    float y = part_s[idx] + part_s[3712 + idx] - cm_s[n]*cs_s[k] + bg_s[k];
    y = (y >= 0.f) ? y : ag * y;
    Ug[idx] = y;
    float s1v = y, s2v = y * y;
    #pragma unroll
    for (int off = 32; off >= 1; off >>= 1) {
      s1v += __shfl_down(s1v, off);
      s2v += __shfl_down(s2v, off);
    }
    if ((tid & 63) == 0) { atomicAdd(&st1_s[n], s1v); atomicAdd(&st2_s[n], s2v); }
  }
  __syncthreads();
  if (tid < 29) {
    float* bn2 = ws + BN2_OFF + (size_t)(b & (SLOTS-1)) * 58;
    atomicAdd(&bn2[tid*2+0], st1_s[tid]);
    atomicAdd(&bn2[tid*2+1], st2_s[tid]);
  }
}

__global__ void k3_finalize2(float* __restrict__ ws) {
  const int n = threadIdx.x; /* 32 */
  if (n < 29) {
    float s1 = 0.f, s2 = 0.f;
    for (int s = 0; s < SLOTS; ++s) {
      s1 += ws[BN2_OFF + s*58 + n*2 + 0];
      s2 += ws[BN2_OFF + s*58 + n*2 + 1];
    }
    const float inv = 1.f / (float)(B_ * D_);
    float mean = s1 * inv, var = s2 * inv - mean * mean;
    ws[M2_OFF + n] = mean;
    ws[IS2_OFF + n] = rsqrtf(var + EPSBN);
  }
}

/* K4: bn2 -> cosine sim vs v -> softmax over n -> pooled @ Wp + bp -> x3, bn3 stats */
__global__ __launch_bounds__(128) void k4_pool(
    const float* __restrict__ Wp, const float* __restrict__ bp,
    float* __restrict__ ws)
{
  __shared__ float x2_s[29*128];
  __shared__ float agg_s[29], m2_s[29], is2_s[29];
  __shared__ float v_s[128], p_s[128];
  __shared__ float r2[58], rv[58];

  const int b = blockIdx.x, k = threadIdx.x;
  const float* y1 = ws + U_OFF + (size_t)b * 3712;
  if (k < 29) { m2_s[k] = ws[M2_OFF + k]; is2_s[k] = ws[IS2_OFF + k]; }
  v_s[k] = ws[V_OFF + k];
  __syncthreads();
  const int wv = k >> 6, lane = k & 63;
  for (int n = 0; n < 29; ++n) {
    float x2 = (y1[n*128 + k] - m2_s[n]) * is2_s[n];
    x2_s[n*128 + k] = x2;
    float ss = x2 * x2, sv = x2 * v_s[k];
    #pragma unroll
    for (int off = 32; off >= 1; off >>= 1) {
      ss += __shfl_down(ss, off);
      sv += __shfl_down(sv, off);
    }
    if (lane == 0) { r2[n*2 + wv] = ss; rv[n*2 + wv] = sv; }
  }
  __syncthreads();
  if (k < 29) {
    float ss = r2[k*2] + r2[k*2+1], sv = rv[k*2] + rv[k*2+1];
    agg_s[k] = sv / (sqrtf(ss) + 1e-8f);
  }
  __syncthreads();
  float mx = -1e30f;
  #pragma unroll
  for (int n = 0; n < 29; ++n) mx = fmaxf(mx, agg_s[n]);
  float den = 0.f, pooled = 0.f;
  #pragma unroll
  for (int n = 0; n < 29; ++n) {
    float e = expf(agg_s[n] - mx);
    den += e;
    pooled += e * x2_s[n*128 + k];
  }
  pooled /= den;
  p_s[k] = pooled;
  __syncthreads();
  float acc = bp[k];
  for (int j = 0; j < 128; ++j) acc += p_s[j] * Wp[j*128 + k];
  ws[X3_OFF + (size_t)b*128 + k] = acc;
  float* bn3 = ws + BN3_OFF + (size_t)(b & (SLOTS-1)) * 256;
  atomicAdd(&bn3[k*2+0], acc);
  atomicAdd(&bn3[k*2+1], acc*acc);
}

__global__ void k4_finalize3(float* __restrict__ ws) {
  const int k = threadIdx.x; /* 128 */
  float s1 = 0.f, s2 = 0.f;
  for (int s = 0; s < SLOTS; ++s) {
    s1 += ws[BN3_OFF + s*256 + k*2 + 0];
    s2 += ws[BN3_OFF + s*256 + k*2 + 1];
  }
  const float inv = 1.f / (float)B_;
  float mean = s1 * inv, var = s2 * inv - mean * mean;
  ws[M3_OFF + k] = mean;
  ws[IS3_OFF + k] = rsqrtf(var + EPSBN);
}

/* K5: bn3 -> prelu(x @ Wm1 + bm1) -> sigmoid(h @ Wm2 + bm2) */
__global__ __launch_bounds__(128) void k5_mlp(
    const float* __restrict__ Wm1, const float* __restrict__ bm1,
    const float* __restrict__ amlp, const float* __restrict__ Wm2,
    const float* __restrict__ bm2, const float* __restrict__ ws,
    float* __restrict__ out)
{
  __shared__ float x_s[128];
  __shared__ float red[2];
  const int b = blockIdx.x, k = threadIdx.x;
  float x = (ws[X3_OFF + (size_t)b*128 + k] - ws[M3_OFF + k]) * ws[IS3_OFF + k];
  x_s[k] = x;
  __syncthreads();
  float h = bm1[k];
  for (int j = 0; j < 128; ++j) h += x_s[j] * Wm1[j*128 + k];
  const float am = amlp[0];
  h = (h >= 0.f) ? h : am * h;
  float r = h * Wm2[k];
  #pragma unroll
  for (int off = 32; off >= 1; off >>= 1) r += __shfl_down(r, off);
  if ((k & 63) == 0) red[k >> 6] = r;
  __syncthreads();
  if (k == 0) {
    float logit = red[0] + red[1] + bm2[0];
    out[b] = 1.f / (1.f + expf(-logit));
  }
}

extern "C" void kernel_launch(void* const* d_in, const int* in_sizes, int n_in,
                              void* d_out, int out_size, void* d_ws, size_t ws_size,
                              hipStream_t stream)
{
  (void)in_sizes; (void)n_in; (void)out_size; (void)ws_size;
  const float* X    = (const float*)d_in[0];
  const float* corr = (const float*)d_in[1];
  const float* wc1  = (const float*)d_in[2];
  const float* bc1  = (const float*)d_in[3];
  const float* wc2  = (const float*)d_in[4];
  const float* bc2  = (const float*)d_in[5];
  const float* wc3  = (const float*)d_in[6];
  const float* bc3  = (const float*)d_in[7];
  const float* acnn = (const float*)d_in[8];
  const float* Wg   = (const float*)d_in[9];
  const float* bg   = (const float*)d_in[10];
  const float* agnn = (const float*)d_in[11];
  const float* cent = (const float*)d_in[12];
  const float* hw   = (const float*)d_in[13];
  const float* Wp   = (const float*)d_in[14];
  const float* bp   = (const float*)d_in[15];
  const float* Wm1  = (const float*)d_in[16];
  const float* bm1  = (const float*)d_in[17];
  const float* amlp = (const float*)d_in[18];
  const float* Wm2  = (const float*)d_in[19];
  const float* bm2  = (const float*)d_in[20];
  float* ws  = (float*)d_ws;
  float* out = (float*)d_out;

  hipMemsetAsync(ws + ACC_OFF, 0, 11904 * sizeof(float), stream);
  k1_conv_gemm<<<ROWS/64, 256, 0, stream>>>(X, Wg, wc1, bc1, wc2, bc2, wc3, bc3, acnn, ws);
  k2_finalize1<<<1, 128, 0, stream>>>(Wg, cent, hw, ws);
  k3_gnn<<<B_, 256, 0, stream>>>(corr, bg, agnn, ws);
  k3_finalize2<<<1, 32, 0, stream>>>(ws);
  k4_pool<<<B_, 128, 0, stream>>>(Wp, bp, ws);
  k4_finalize3<<<1, 128, 0, stream>>>(ws);
  k5_mlp<<<B_, 128, 0, stream>>>(Wm1, bm1, amlp, Wm2, bm2, ws, out);
}

// Round 2
// 628.117 us; speedup vs baseline: 1.5743x; 1.5743x over previous
//
#include <hip/hip_runtime.h>

#define B_    8192
#define N_    29
#define F_    147
#define DC    429
#define D_    128
#define ROWS  (B_*N_)          /* 237568 */
#define EPSBN 1e-5f
#define SLOTS 32

/* ws layout in float units */
#define U_OFF    0                          /* bf16 U / y1: ROWS*128 shorts = ROWS*64 floats */
#define X3_OFF   (ROWS*64)                  /* fp32 B_*128 */
#define ACC_OFF  (X3_OFF + B_*D_)
#define BN1_OFF  (ACC_OFF)                  /* 32*29*2 */
#define BN2_OFF  (ACC_OFF + 1856)
#define BN3_OFF  (ACC_OFF + 3712)           /* 32*128*2 */
#define FIN_OFF  (ACC_OFF + 11904)
#define M1_OFF   (FIN_OFF + 0)
#define IS1_OFF  (FIN_OFF + 32)
#define M2_OFF   (FIN_OFF + 64)
#define IS2_OFF  (FIN_OFF + 96)
#define M3_OFF   (FIN_OFF + 128)
#define IS3_OFF  (FIN_OFF + 256)
#define CSW_OFF  (FIN_OFF + 384)
#define V_OFF    (FIN_OFF + 512)
#define IMG_OFF  (FIN_OFF + 1024)           /* bf16 Wg image: 7*128*72 shorts */

typedef __bf16 bf16x8 __attribute__((ext_vector_type(8)));
typedef float  f32x4  __attribute__((ext_vector_type(4)));

__device__ __forceinline__ unsigned short f2bf(float f) {
  unsigned int u = __float_as_uint(f);
  u += 0x7fffu + ((u >> 16) & 1u);
  return (unsigned short)(u >> 16);
}
__device__ __forceinline__ float bf2f(unsigned short u) {
  return __uint_as_float(((unsigned)u) << 16);
}

/* async global->LDS: per-lane g address; LDS dst = uniform base + lane*size */
__device__ __forceinline__ void stage16(const void* g_lane, void* l_uniform) {
  __builtin_amdgcn_global_load_lds((const __attribute__((address_space(1))) void*)g_lane,
                                   (__attribute__((address_space(3))) void*)l_uniform, 16, 0, 0);
}
__device__ __forceinline__ void stage4(const void* g_lane, void* l_uniform) {
  __builtin_amdgcn_global_load_lds((const __attribute__((address_space(1))) void*)g_lane,
                                   (__attribute__((address_space(3))) void*)l_uniform, 4, 0, 0);
}

#define TSTR 456   /* 448+8 shorts */
#define WSTR 72    /* 64+8 shorts; img layout must match */

/* K0: Wg -> bf16 staged image; colsum(Wg); v = sum_h hw[h]*normalize(cent[h]) */
__global__ void k0_prep(const float* __restrict__ Wg,
                        const float* __restrict__ cent,
                        const float* __restrict__ hw,
                        float* __restrict__ ws)
{
  const int tid = threadIdx.x; /* 256 */
  unsigned short* img = (unsigned short*)(ws + IMG_OFF);
  for (int i = tid; i < 7*128*64; i += 256) {
    int ks = i >> 13;
    int rem = i & 8191;
    int k = rem >> 6, dd = rem & 63;
    int d = ks*64 + dd;
    float w = (d < DC) ? Wg[d*D_ + k] : 0.f;
    img[ks*(128*WSTR) + k*WSTR + dd] = f2bf(w);
  }
  if (tid < D_) {
    float cs = 0.f;
    for (int d = 0; d < DC; ++d) cs += Wg[d*D_ + tid];
    ws[CSW_OFF + tid] = cs;
  }
  __shared__ float sq[128];
  __shared__ float nrm;
  float vk = 0.f;
  for (int h = 0; h < 4; ++h) {
    float c = (tid < 128) ? cent[h*D_ + tid] : 0.f;
    if (tid < 128) sq[tid] = c*c;
    __syncthreads();
    if (tid == 0) { float s = 0.f; for (int j = 0; j < 128; ++j) s += sq[j]; nrm = sqrtf(s) + 1e-8f; }
    __syncthreads();
    if (tid < 128) vk += hw[h] * c / nrm;
    __syncthreads();
  }
  if (tid < 128) ws[V_OFF + tid] = vk;
}

/* K1: sliding-window conv + prelu -> t (bf16 LDS); bn1 stats; U = t@Wg (MFMA, bf16 out) */
__global__ __launch_bounds__(256, 2) void k1_conv_gemm(
    const float* __restrict__ X,
    const float* __restrict__ wc1, const float* __restrict__ bc1,
    const float* __restrict__ wc2, const float* __restrict__ bc2,
    const float* __restrict__ wc3, const float* __restrict__ bc3,
    const float* __restrict__ acnn, float* __restrict__ ws)
{
  __shared__ unsigned short t_s[64*TSTR];                 /* 58368 B */
  __shared__ __align__(16) unsigned char ubuf[32*F_*4];   /* 18816 B: X half-tile, then Wg stage (18432) */
  __shared__ float st1[29], st2[29];

  const int tid = threadIdx.x;
  const int row0 = blockIdx.x * 64;
  const int wv = tid >> 6, lane = tid & 63;

  if (tid < 29) { st1[tid] = 0.f; st2[tid] = 0.f; }
  for (int i = tid; i < 64*19; i += 256) {        /* zero t pad cols 429..447 */
    int r = i / 19, c = i - r*19;
    t_s[r*TSTR + DC + c] = 0;
  }

  const float c10 = wc1[0], c11 = wc1[1], c12 = wc1[2], b1 = bc1[0];
  const float c20 = wc2[0], c21 = wc2[1], c22 = wc2[2], c23 = wc2[3], c24 = wc2[4], b2 = bc2[0];
  const float c30 = wc3[0], c31 = wc3[1], c32 = wc3[2], c33 = wc3[3], c34 = wc3[4],
              c35 = wc3[5], c36 = wc3[6], b3 = bc3[0];
  const float ap = acnn[0];

  float* xs = (float*)ubuf;
  for (int h = 0; h < 2; ++h) {
    __syncthreads();
    const float* xsrc = X + (size_t)(row0 + 32*h) * F_;
    for (int i = tid; i < 32*F_; i += 256) xs[i] = xsrc[i];
    __syncthreads();
    const int r = tid >> 3, q = tid & 7;
    const int rloc = 32*h + r;
    const int f0 = q*19, f1 = (f0+19 < F_) ? f0+19 : F_;
    const float* xr = xs + r*F_;
    unsigned short* tr = t_s + rloc*TSTR;
    /* f0 <= 133 so f0+5 <= 138 < 147: unguarded preload */
    float wA = xr[f0], wB = xr[f0+1], wC = xr[f0+2], wD = xr[f0+3], wE = xr[f0+4], wF = xr[f0+5], wG;
    float s1 = 0.f, s2 = 0.f;
    for (int f = f0; f < f1; ++f) {
      wG = (f+6 < F_) ? xr[f+6] : 0.f;
      if (f < 145) {
        float v = fmaf(wA,c10, fmaf(wB,c11, fmaf(wC,c12, b1)));
        v = (v >= 0.f) ? v : ap*v;
        s1 += v; s2 = fmaf(v, v, s2);
        tr[f] = f2bf(v);
      }
      if (f < 143) {
        float v = fmaf(wA,c20, fmaf(wB,c21, fmaf(wC,c22, fmaf(wD,c23, fmaf(wE,c24, b2)))));
        v = (v >= 0.f) ? v : ap*v;
        s1 += v; s2 = fmaf(v, v, s2);
        tr[145+f] = f2bf(v);
      }
      if (f < 141) {
        float v = fmaf(wA,c30, fmaf(wB,c31, fmaf(wC,c32, fmaf(wD,c33, fmaf(wE,c34, fmaf(wF,c35, fmaf(wG,c36, b3)))))));
        v = (v >= 0.f) ? v : ap*v;
        s1 += v; s2 = fmaf(v, v, s2);
        tr[288+f] = f2bf(v);
      }
      wA = wB; wB = wC; wC = wD; wD = wE; wE = wF; wF = wG;
    }
    int m = (row0 + rloc) % 29;
    atomicAdd(&st1[m], s1);
    atomicAdd(&st2[m], s2);
  }
  __syncthreads();
  if (tid < 29) {
    float* bn1 = ws + BN1_OFF + (size_t)(blockIdx.x & (SLOTS-1)) * 58;
    atomicAdd(&bn1[tid*2+0], st1[tid]);
    atomicAdd(&bn1[tid*2+1], st2[tid]);
  }

  /* ---- phase B: MFMA, Wg staged via global_load_lds from pre-swizzled image ---- */
  const unsigned short* img = (const unsigned short*)(ws + IMG_OFF);
  unsigned short* wg_s = (unsigned short*)ubuf;
  const int lrow = lane & 15, quad = lane >> 4;
  const int rbase = (wv & 1) * 32, cbase = (wv >> 1) * 64;
  f32x4 acc[2][4];
  #pragma unroll
  for (int rt = 0; rt < 2; ++rt)
    #pragma unroll
    for (int nt = 0; nt < 4; ++nt)
      acc[rt][nt] = (f32x4){0.f, 0.f, 0.f, 0.f};

  for (int ks = 0; ks < 7; ++ks) {
    __syncthreads();
    {
      const unsigned char* gsrc = (const unsigned char*)(img + ks*(128*WSTR));
      unsigned char* ldst = (unsigned char*)wg_s;
      for (int j = wv; j < 18; j += 4)
        stage16(gsrc + j*1024 + lane*16, ldst + j*1024);
    }
    __syncthreads();
    #pragma unroll
    for (int kk = 0; kk < 2; ++kk) {
      bf16x8 a0 = *(const bf16x8*)&t_s[(rbase      + lrow)*TSTR + ks*64 + kk*32 + quad*8];
      bf16x8 a1 = *(const bf16x8*)&t_s[(rbase + 16 + lrow)*TSTR + ks*64 + kk*32 + quad*8];
      #pragma unroll
      for (int nt = 0; nt < 4; ++nt) {
        bf16x8 bfr = *(const bf16x8*)&wg_s[(cbase + nt*16 + lrow)*WSTR + kk*32 + quad*8];
        acc[0][nt] = __builtin_amdgcn_mfma_f32_16x16x32_bf16(a0, bfr, acc[0][nt], 0, 0, 0);
        acc[1][nt] = __builtin_amdgcn_mfma_f32_16x16x32_bf16(a1, bfr, acc[1][nt], 0, 0, 0);
      }
    }
  }

  unsigned short* U16 = (unsigned short*)ws;
  #pragma unroll
  for (int rt = 0; rt < 2; ++rt)
    #pragma unroll
    for (int nt = 0; nt < 4; ++nt)
      #pragma unroll
      for (int i = 0; i < 4; ++i) {
        int r = row0 + rbase + rt*16 + quad*4 + i;
        int c = cbase + nt*16 + lrow;
        U16[(size_t)r * D_ + c] = f2bf(acc[rt][nt][i]);
      }
}

/* K2: finalize bn1 */
__global__ void k2_bn1(float* __restrict__ ws) {
  const int k = threadIdx.x; /* 32 */
  if (k < 29) {
    float s1 = 0.f, s2 = 0.f;
    for (int s = 0; s < SLOTS; ++s) {
      s1 += ws[BN1_OFF + s*58 + k*2 + 0];
      s2 += ws[BN1_OFF + s*58 + k*2 + 1];
    }
    const float inv = 1.f / (float)(B_ * DC);
    float mean = s1 * inv;
    float var  = s2 * inv - mean * mean;
    ws[M1_OFF  + k] = mean;
    ws[IS1_OFF + k] = rsqrtf(var + EPSBN);
  }
}

/* K3: y1 = prelu(corr @ bn1(t) @ Wg + bg) via MFMA in 128-dim; bn2 stats; in-place bf16 */
__global__ __launch_bounds__(256) void k3_gnn(
    const float* __restrict__ corr, const float* __restrict__ bg,
    const float* __restrict__ agnn, float* __restrict__ ws)
{
  __shared__ float cwf[841];
  __shared__ unsigned short a_s[32*40];
  __shared__ unsigned short ut[128*40];
  __shared__ __align__(16) unsigned short urow[3712];
  __shared__ float m1s[29], is1s[29], cms[29], css[128], bgs[128], st1s[29], st2s[29];

  const int b = blockIdx.x, tid = threadIdx.x;
  const int wv = tid >> 6, lane = tid & 63;
  unsigned short* U16 = (unsigned short*)ws;
  unsigned short* Ub = U16 + (size_t)b * 3712;

  if (wv == 0) {   /* async stage U rows (29x128 bf16, 7424 B) */
    const unsigned char* g = (const unsigned char*)Ub;
    unsigned char* l = (unsigned char*)urow;
    #pragma unroll
    for (int j = 0; j < 7; ++j) stage16(g + j*1024 + lane*16, l + j*1024);
    stage4(g + 7168 + lane*4, l + 7168);
  }
  if (tid < 29) { m1s[tid] = ws[M1_OFF+tid]; is1s[tid] = ws[IS1_OFF+tid]; st1s[tid] = 0.f; st2s[tid] = 0.f; }
  if (tid >= 32 && tid < 160) { css[tid-32] = ws[CSW_OFF + tid-32]; bgs[tid-32] = bg[tid-32]; }
  const float* cb = corr + (size_t)b * 841;
  for (int i = tid; i < 841; i += 256) cwf[i] = cb[i];
  __syncthreads();   /* drains vmcnt: urow + cwf ready */

  for (int i = tid; i < 32*32; i += 256) {
    int n = i >> 5, m = i & 31;
    float v = (n < 29 && m < 29) ? cwf[n*29 + m] * is1s[m] : 0.f;
    a_s[n*40 + m] = f2bf(v);
  }
  if (tid < 29) {
    float cm = 0.f;
    for (int m = 0; m < 29; ++m) cm += cwf[tid*29 + m] * is1s[m] * m1s[m];
    cms[tid] = cm;
  }
  /* transpose urow(29x128) -> ut(128 x stride 40), zero K-pad m=29..31 */
  for (int i = tid; i < 128*4; i += 256) {
    int kf = i >> 2, m = 28 + (i & 3);
    if (m >= 29) ut[kf*40 + m] = 0;
  }
  for (int i = tid; i < 1856; i += 256) {
    int m = i >> 6, k2 = i & 63;
    unsigned v = ((const unsigned*)urow)[i];
    int kf = k2 * 2;
    ut[kf*40 + m]     = (unsigned short)(v & 0xffffu);
    ut[(kf+1)*40 + m] = (unsigned short)(v >> 16);
  }
  __syncthreads();

  const int lrow = lane & 15, quad = lane >> 4;
  f32x4 acc[2][2];
  #pragma unroll
  for (int mt = 0; mt < 2; ++mt)
    #pragma unroll
    for (int j = 0; j < 2; ++j)
      acc[mt][j] = (f32x4){0.f, 0.f, 0.f, 0.f};

  bf16x8 afr0 = *(const bf16x8*)&a_s[lrow*40 + quad*8];
  bf16x8 afr1 = *(const bf16x8*)&a_s[(16+lrow)*40 + quad*8];
  #pragma unroll
  for (int j = 0; j < 2; ++j) {
    int feat0 = (wv*2 + j) * 16;
    bf16x8 bfr = *(const bf16x8*)&ut[(feat0 + lrow)*40 + quad*8];
    acc[0][j] = __builtin_amdgcn_mfma_f32_16x16x32_bf16(afr0, bfr, acc[0][j], 0, 0, 0);
    acc[1][j] = __builtin_amdgcn_mfma_f32_16x16x32_bf16(afr1, bfr, acc[1][j], 0, 0, 0);
  }

  const float ag = agnn[0];
  #pragma unroll
  for (int mt = 0; mt < 2; ++mt) {
    #pragma unroll
    for (int i = 0; i < 4; ++i) {
      int n = mt*16 + quad*4 + i;
      bool valid = (n < 29);
      int nc = valid ? n : 28;
      float ys = 0.f, ys2 = 0.f;
      #pragma unroll
      for (int j = 0; j < 2; ++j) {
        int feat = (wv*2 + j)*16 + lrow;
        float y = acc[mt][j][i] - cms[nc]*css[feat] + bgs[feat];
        y = (y >= 0.f) ? y : ag*y;
        if (valid) {
          Ub[n*D_ + feat] = f2bf(y);
          ys += y; ys2 = fmaf(y, y, ys2);
        }
      }
      #pragma unroll
      for (int off = 8; off >= 1; off >>= 1) {
        ys  += __shfl_xor(ys, off);
        ys2 += __shfl_xor(ys2, off);
      }
      if (valid && lrow == 0) { atomicAdd(&st1s[n], ys); atomicAdd(&st2s[n], ys2); }
    }
  }
  __syncthreads();
  if (tid < 29) {
    float* bn2 = ws + BN2_OFF + (size_t)(b & (SLOTS-1)) * 58;
    atomicAdd(&bn2[tid*2+0], st1s[tid]);
    atomicAdd(&bn2[tid*2+1], st2s[tid]);
  }
}

__global__ void k3_finalize2(float* __restrict__ ws) {
  const int n = threadIdx.x; /* 32 */
  if (n < 29) {
    float s1 = 0.f, s2 = 0.f;
    for (int s = 0; s < SLOTS; ++s) {
      s1 += ws[BN2_OFF + s*58 + n*2 + 0];
      s2 += ws[BN2_OFF + s*58 + n*2 + 1];
    }
    const float inv = 1.f / (float)(B_ * D_);
    float mean = s1 * inv, var = s2 * inv - mean * mean;
    ws[M2_OFF + n] = mean;
    ws[IS2_OFF + n] = rsqrtf(var + EPSBN);
  }
}

/* K4: bn2 -> cosine sim vs v -> softmax(n) -> pooled @ Wp + bp -> x3, bn3 stats */
__global__ __launch_bounds__(128) void k4_pool(
    const float* __restrict__ Wp, const float* __restrict__ bp,
    float* __restrict__ ws)
{
  __shared__ float x2_s[29*128];
  __shared__ float agg_s[29], m2_s[29], is2_s[29];
  __shared__ float v_s[128], p_s[128];
  __shared__ float r2[58], rv[58];

  const int b = blockIdx.x, k = threadIdx.x;
  const unsigned short* y1 = (const unsigned short*)ws + (size_t)b * 3712;
  if (k < 29) { m2_s[k] = ws[M2_OFF + k]; is2_s[k] = ws[IS2_OFF + k]; }
  v_s[k] = ws[V_OFF + k];
  __syncthreads();
  const int wv = k >> 6, lane = k & 63;
  for (int n = 0; n < 29; ++n) {
    float x2 = (bf2f(y1[n*128 + k]) - m2_s[n]) * is2_s[n];
    x2_s[n*128 + k] = x2;
    float ss = x2 * x2, sv = x2 * v_s[k];
    #pragma unroll
    for (int off = 32; off >= 1; off >>= 1) {
      ss += __shfl_down(ss, off);
      sv += __shfl_down(sv, off);
    }
    if (lane == 0) { r2[n*2 + wv] = ss; rv[n*2 + wv] = sv; }
  }
  __syncthreads();
  if (k < 29) {
    float ss = r2[k*2] + r2[k*2+1], sv = rv[k*2] + rv[k*2+1];
    agg_s[k] = sv / (sqrtf(ss) + 1e-8f);
  }
  __syncthreads();
  float mx = -1e30f;
  #pragma unroll
  for (int n = 0; n < 29; ++n) mx = fmaxf(mx, agg_s[n]);
  float den = 0.f, pooled = 0.f;
  #pragma unroll
  for (int n = 0; n < 29; ++n) {
    float e = expf(agg_s[n] - mx);
    den += e;
    pooled += e * x2_s[n*128 + k];
  }
  pooled /= den;
  p_s[k] = pooled;
  __syncthreads();
  float acc = bp[k];
  for (int j = 0; j < 128; ++j) acc += p_s[j] * Wp[j*128 + k];
  ws[X3_OFF + (size_t)b*128 + k] = acc;
  float* bn3 = ws + BN3_OFF + (size_t)(b & (SLOTS-1)) * 256;
  atomicAdd(&bn3[k*2+0], acc);
  atomicAdd(&bn3[k*2+1], acc*acc);
}

__global__ void k4_finalize3(float* __restrict__ ws) {
  const int k = threadIdx.x; /* 128 */
  float s1 = 0.f, s2 = 0.f;
  for (int s = 0; s < SLOTS; ++s) {
    s1 += ws[BN3_OFF + s*256 + k*2 + 0];
    s2 += ws[BN3_OFF + s*256 + k*2 + 1];
  }
  const float inv = 1.f / (float)B_;
  float mean = s1 * inv, var = s2 * inv - mean * mean;
  ws[M3_OFF + k] = mean;
  ws[IS3_OFF + k] = rsqrtf(var + EPSBN);
}

/* K5: bn3 -> prelu(x @ Wm1 + bm1) -> sigmoid(h @ Wm2 + bm2) */
__global__ __launch_bounds__(128) void k5_mlp(
    const float* __restrict__ Wm1, const float* __restrict__ bm1,
    const float* __restrict__ amlp, const float* __restrict__ Wm2,
    const float* __restrict__ bm2, const float* __restrict__ ws,
    float* __restrict__ out)
{
  __shared__ float x_s[128];
  __shared__ float red[2];
  const int b = blockIdx.x, k = threadIdx.x;
  float x = (ws[X3_OFF + (size_t)b*128 + k] - ws[M3_OFF + k]) * ws[IS3_OFF + k];
  x_s[k] = x;
  __syncthreads();
  float h = bm1[k];
  for (int j = 0; j < 128; ++j) h += x_s[j] * Wm1[j*128 + k];
  const float am = amlp[0];
  h = (h >= 0.f) ? h : am * h;
  float r = h * Wm2[k];
  #pragma unroll
  for (int off = 32; off >= 1; off >>= 1) r += __shfl_down(r, off);
  if ((k & 63) == 0) red[k >> 6] = r;
  __syncthreads();
  if (k == 0) {
    float logit = red[0] + red[1] + bm2[0];
    out[b] = 1.f / (1.f + expf(-logit));
  }
}

extern "C" void kernel_launch(void* const* d_in, const int* in_sizes, int n_in,
                              void* d_out, int out_size, void* d_ws, size_t ws_size,
                              hipStream_t stream)
{
  (void)in_sizes; (void)n_in; (void)out_size; (void)ws_size;
  const float* X    = (const float*)d_in[0];
  const float* corr = (const float*)d_in[1];
  const float* wc1  = (const float*)d_in[2];
  const float* bc1  = (const float*)d_in[3];
  const float* wc2  = (const float*)d_in[4];
  const float* bc2  = (const float*)d_in[5];
  const float* wc3  = (const float*)d_in[6];
  const float* bc3  = (const float*)d_in[7];
  const float* acnn = (const float*)d_in[8];
  const float* Wg   = (const float*)d_in[9];
  const float* bg   = (const float*)d_in[10];
  const float* agnn = (const float*)d_in[11];
  const float* cent = (const float*)d_in[12];
  const float* hw   = (const float*)d_in[13];
  const float* Wp   = (const float*)d_in[14];
  const float* bp   = (const float*)d_in[15];
  const float* Wm1  = (const float*)d_in[16];
  const float* bm1  = (const float*)d_in[17];
  const float* amlp = (const float*)d_in[18];
  const float* Wm2  = (const float*)d_in[19];
  const float* bm2  = (const float*)d_in[20];
  float* ws  = (float*)d_ws;
  float* out = (float*)d_out;

  hipMemsetAsync(ws + ACC_OFF, 0, 11904 * sizeof(float), stream);
  k0_prep<<<1, 256, 0, stream>>>(Wg, cent, hw, ws);
  k1_conv_gemm<<<ROWS/64, 256, 0, stream>>>(X, wc1, bc1, wc2, bc2, wc3, bc3, acnn, ws);
  k2_bn1<<<1, 32, 0, stream>>>(ws);
  k3_gnn<<<B_, 256, 0, stream>>>(corr, bg, agnn, ws);
  k3_finalize2<<<1, 32, 0, stream>>>(ws);
  k4_pool<<<B_, 128, 0, stream>>>(Wp, bp, ws);
  k4_finalize3<<<1, 128, 0, stream>>>(ws);
  k5_mlp<<<B_, 128, 0, stream>>>(Wm1, bm1, amlp, Wm2, bm2, ws, out);
}

// Round 3
// 624.465 us; speedup vs baseline: 1.5835x; 1.0058x over previous
//
#include <hip/hip_runtime.h>

#define B_    8192
#define N_    29
#define F_    147
#define DC    429
#define D_    128
#define ROWS  (B_*N_)          /* 237568 */
#define EPSBN 1e-5f

/* Ut: per-b 4096 shorts: [f:128][m:32] bf16, m=29..31 zero; y1 overwrites in-place
   as [n:29][d:128] bf16 (3712 shorts); rowstats (29*3 fp32) at short-offset 3712. */
#define UTSTR   4096                        /* shorts per b */
#define RS_SH   3712                        /* short offset of rowstats */

/* ws layout in float units */
#define X3_OFF   16777216                   /* fp32 B_*128 */
#define ACC_OFF  (X3_OFF + B_*D_)           /* 17825792 */
#define BN1_OFF  (ACC_OFF)                  /* 32*29*2 */
#define BN2_OFF  (ACC_OFF + 1856)
#define BN3_OFF  (ACC_OFF + 3712)           /* 32*128*2 */
#define FIN_OFF  (ACC_OFF + 11904)
#define M1_OFF   (FIN_OFF + 0)
#define IS1_OFF  (FIN_OFF + 32)
#define M2_OFF   (FIN_OFF + 64)
#define IS2_OFF  (FIN_OFF + 96)
#define M3_OFF   (FIN_OFF + 128)
#define IS3_OFF  (FIN_OFF + 256)
#define CSW_OFF  (FIN_OFF + 384)
#define V_OFF    (FIN_OFF + 512)
#define V1_OFF   (FIN_OFF + 640)
#define IMG_OFF  (FIN_OFF + 1024)           /* bf16 Wg image: 128*448 shorts n-major */

typedef __bf16 bf16x8 __attribute__((ext_vector_type(8)));
typedef float  f32x4  __attribute__((ext_vector_type(4)));

__device__ __forceinline__ unsigned short f2bf(float f) {
  unsigned int u = __float_as_uint(f);
  u += 0x7fffu + ((u >> 16) & 1u);
  return (unsigned short)(u >> 16);
}
__device__ __forceinline__ float bf2f(unsigned u16) {
  return __uint_as_float(u16 << 16);
}

#define TSTR 456   /* 448+8 shorts: 4-bank rotation per row */

/* K0a: build bf16 Wg image, n-major [128][448], rows shifted to t-layout
   (dk: 0..144 conv1, 145 pad, 146..288 conv2, 289 pad, 290..430 conv3, 431..447 pad);
   also colsum(Wg). grid 16 x 256. */
__global__ void k0a_img(const float* __restrict__ Wg, float* __restrict__ ws)
{
  __shared__ float cs_l[8];
  const int tid = threadIdx.x;
  const int kb = blockIdx.x * 8;
  if (tid < 8) cs_l[tid] = 0.f;
  __syncthreads();
  unsigned short* img = (unsigned short*)(ws + IMG_OFF);
  for (int i = tid; i < 8*448; i += 256) {
    int kk = i / 448, dk = i - kk*448;
    int k = kb + kk;
    int d;
    if      (dk < 145)  d = dk;
    else if (dk == 145) d = -1;
    else if (dk < 289)  d = dk - 1;
    else if (dk == 289) d = -1;
    else if (dk < 431)  d = dk - 2;
    else                d = -1;
    float v = (d >= 0) ? Wg[(size_t)d*D_ + k] : 0.f;
    img[(size_t)k*448 + dk] = f2bf(v);
    if (d >= 0) atomicAdd(&cs_l[kk], v);
  }
  __syncthreads();
  if (tid < 8) ws[CSW_OFF + kb + tid] = cs_l[tid];
}

/* K0b: v = sum_h hw[h]*normalize(cent[h]); V1 = sum(v). 1 x 128 */
__global__ void k0b_cent(const float* __restrict__ cent, const float* __restrict__ hw,
                         float* __restrict__ ws)
{
  __shared__ float sq[128];
  __shared__ float nrm;
  const int tid = threadIdx.x;
  float vk = 0.f;
  for (int h = 0; h < 4; ++h) {
    float c = cent[h*D_ + tid];
    sq[tid] = c*c;
    __syncthreads();
    if (tid == 0) { float s=0.f; for (int j=0;j<128;++j) s+=sq[j]; nrm = sqrtf(s)+1e-8f; }
    __syncthreads();
    vk += hw[h] * c / nrm;
    __syncthreads();
  }
  ws[V_OFF + tid] = vk;
  sq[tid] = vk;
  __syncthreads();
  if (tid == 0) { float s=0.f; for (int j=0;j<128;++j) s+=sq[j]; ws[V1_OFF] = s; }
}

/* K1: sliding conv + prelu -> t_s (bf16 LDS); bn1 stats; Ut = (t@Wg)^T-ish store.
   512 threads, barrier-free MFMA K-loop with direct-global B frags. */
__global__ __launch_bounds__(512, 4) void k1_conv_gemm(
    const float* __restrict__ X,
    const float* __restrict__ wc1, const float* __restrict__ bc1,
    const float* __restrict__ wc2, const float* __restrict__ bc2,
    const float* __restrict__ wc3, const float* __restrict__ bc3,
    const float* __restrict__ acnn, float* __restrict__ ws)
{
  __shared__ unsigned short t_s[64*TSTR];          /* 58368 B */
  __shared__ __align__(16) float xs[32*F_];        /* 18816 B */
  __shared__ float st1[29], st2[29];

  const int tid = threadIdx.x;
  const int row0 = blockIdx.x * 64;

  if (tid < 29) { st1[tid] = 0.f; st2[tid] = 0.f; }
  for (int i = tid; i < 64*19; i += 512) {         /* zero pad cols 145,289,431..447 */
    int r = i / 19, j = i - r*19;
    int col = (j == 0) ? 145 : ((j == 1) ? 289 : (429 + j));
    t_s[r*TSTR + col] = 0;
  }

  const float c10 = wc1[0], c11 = wc1[1], c12 = wc1[2], b1 = bc1[0];
  const float c20 = wc2[0], c21 = wc2[1], c22 = wc2[2], c23 = wc2[3], c24 = wc2[4], b2 = bc2[0];
  const float c30 = wc3[0], c31 = wc3[1], c32 = wc3[2], c33 = wc3[3], c34 = wc3[4],
              c35 = wc3[5], c36 = wc3[6], b3 = bc3[0];
  const float ap = acnn[0];

  const int r  = tid >> 4;          /* 0..31 */
  const int q  = tid & 15;
  const int f0 = q * 10;
  const int cnt = (f0 < F_) ? ((f0 + 10 < F_) ? 10 : F_ - f0) : 0;

  for (int h = 0; h < 2; ++h) {
    __syncthreads();
    const float* xsrc = X + (size_t)(row0 + 32*h) * F_;
    for (int i = tid; i < 32*F_; i += 512) xs[i] = xsrc[i];
    __syncthreads();
    if (f0 < 145) {
      const int rloc = 32*h + r;
      const float* xr = xs + r*F_;
      unsigned short* tr = t_s + rloc*TSTR;
      unsigned int* tr32 = (unsigned int*)tr;
      float wA=xr[f0],wB=xr[f0+1],wC=xr[f0+2],wD=xr[f0+3],wE=xr[f0+4],wF=xr[f0+5],wG;
      const int n1 = min(cnt, 145 - f0);
      const int n2 = min(cnt, 143 - f0);
      const int n3 = min(cnt, 141 - f0);
      float o1[10], o2[10], o3[10];
      float s1 = 0.f, s2 = 0.f;
      #pragma unroll
      for (int i2 = 0; i2 < 10; ++i2) {
        if (i2 < cnt) {
          int f = f0 + i2;
          wG = (f + 6 < F_) ? xr[f+6] : 0.f;
          float v1 = fmaf(wA,c10, fmaf(wB,c11, fmaf(wC,c12, b1)));
          v1 = (v1 >= 0.f) ? v1 : ap*v1;
          float v2 = fmaf(wA,c20, fmaf(wB,c21, fmaf(wC,c22, fmaf(wD,c23, fmaf(wE,c24, b2)))));
          v2 = (v2 >= 0.f) ? v2 : ap*v2;
          float v3 = fmaf(wA,c30, fmaf(wB,c31, fmaf(wC,c32, fmaf(wD,c33, fmaf(wE,c34, fmaf(wF,c35, fmaf(wG,c36, b3)))))));
          v3 = (v3 >= 0.f) ? v3 : ap*v3;
          o1[i2] = v1; o2[i2] = v2; o3[i2] = v3;
          if (i2 < n1) { s1 += v1; s2 = fmaf(v1, v1, s2); }
          if (i2 < n2) { s1 += v2; s2 = fmaf(v2, v2, s2); }
          if (i2 < n3) { s1 += v3; s2 = fmaf(v3, v3, s2); }
          wA=wB; wB=wC; wC=wD; wD=wE; wE=wF; wF=wG;
        }
      }
      #pragma unroll
      for (int i2 = 0; i2 < 10; i2 += 2) {
        if (i2+1 < n1)      tr32[(f0+i2)>>1] = (unsigned)f2bf(o1[i2]) | ((unsigned)f2bf(o1[i2+1])<<16);
        else if (i2 < n1)   tr[f0+i2] = f2bf(o1[i2]);
        if (i2+1 < n2)      tr32[(146+f0+i2)>>1] = (unsigned)f2bf(o2[i2]) | ((unsigned)f2bf(o2[i2+1])<<16);
        else if (i2 < n2)   tr[146+f0+i2] = f2bf(o2[i2]);
        if (i2+1 < n3)      tr32[(290+f0+i2)>>1] = (unsigned)f2bf(o3[i2]) | ((unsigned)f2bf(o3[i2+1])<<16);
        else if (i2 < n3)   tr[290+f0+i2] = f2bf(o3[i2]);
      }
      int m = (row0 + rloc) % 29;
      atomicAdd(&st1[m], s1);
      atomicAdd(&st2[m], s2);
    }
  }
  __syncthreads();
  if (tid < 29) {
    float* bn1 = ws + BN1_OFF + (size_t)(blockIdx.x & 31) * 58;
    atomicAdd(&bn1[tid*2+0], st1[tid]);
    atomicAdd(&bn1[tid*2+1], st2[tid]);
  }

  /* ---- phase B: barrier-free K-loop. 8 waves: 2 row-groups x 4 col-groups ---- */
  const int wv = tid >> 6, lane = tid & 63;
  const int lrow = lane & 15, quad = lane >> 4;
  const int rbase = (wv >> 2) * 32;
  const int n0 = (wv & 3) * 32;
  const unsigned short* imgp = (const unsigned short*)(ws + IMG_OFF);
  const unsigned short* gB0 = imgp + (size_t)(n0 + lrow)*448 + quad*8;
  const unsigned short* gB1 = imgp + (size_t)(n0 + 16 + lrow)*448 + quad*8;

  f32x4 acc[2][2];
  #pragma unroll
  for (int rt = 0; rt < 2; ++rt)
    #pragma unroll
    for (int nt = 0; nt < 2; ++nt)
      acc[rt][nt] = (f32x4){0.f, 0.f, 0.f, 0.f};

  #pragma unroll
  for (int ks = 0; ks < 14; ++ks) {
    const int k0 = ks * 32;
    bf16x8 A0 = *(const bf16x8*)&t_s[(rbase      + lrow)*TSTR + k0 + quad*8];
    bf16x8 A1 = *(const bf16x8*)&t_s[(rbase + 16 + lrow)*TSTR + k0 + quad*8];
    bf16x8 B0 = *(const bf16x8*)(gB0 + k0);
    bf16x8 B1 = *(const bf16x8*)(gB1 + k0);
    acc[0][0] = __builtin_amdgcn_mfma_f32_16x16x32_bf16(A0, B0, acc[0][0], 0, 0, 0);
    acc[0][1] = __builtin_amdgcn_mfma_f32_16x16x32_bf16(A0, B1, acc[0][1], 0, 0, 0);
    acc[1][0] = __builtin_amdgcn_mfma_f32_16x16x32_bf16(A1, B0, acc[1][0], 0, 0, 0);
    acc[1][1] = __builtin_amdgcn_mfma_f32_16x16x32_bf16(A1, B1, acc[1][1], 0, 0, 0);
  }

  /* epilogue: Ut[b][c][m32] bf16; zero m=29..31 when n==28 */
  unsigned short* U16 = (unsigned short*)ws;
  #pragma unroll
  for (int rt = 0; rt < 2; ++rt)
    #pragma unroll
    for (int i = 0; i < 4; ++i) {
      int rrow = row0 + rbase + rt*16 + quad*4 + i;
      int b = rrow / 29;
      int n = rrow - b*29;
      size_t basesh = (size_t)b * UTSTR + n;
      #pragma unroll
      for (int nt = 0; nt < 2; ++nt) {
        int c = n0 + nt*16 + lrow;
        unsigned short* p = U16 + basesh + (size_t)c*32;
        *p = f2bf(acc[rt][nt][i]);
        if (n == 28) { p[1] = 0; p[2] = 0; p[3] = 0; }
      }
    }
}

/* K2: finalize bn1 */
__global__ void k2_bn1(float* __restrict__ ws) {
  const int k = threadIdx.x; /* 32 */
  if (k < 29) {
    float s1 = 0.f, s2 = 0.f;
    for (int s = 0; s < 32; ++s) {
      s1 += ws[BN1_OFF + s*58 + k*2 + 0];
      s2 += ws[BN1_OFF + s*58 + k*2 + 1];
    }
    const float inv = 1.f / (float)(B_ * DC);
    float mean = s1 * inv;
    float var  = s2 * inv - mean * mean;
    ws[M1_OFF  + k] = mean;
    ws[IS1_OFF + k] = rsqrtf(var + EPSBN);
  }
}

/* K3: y1 = prelu(corr@bn1(t)@Wg + bg); per-(b,n) rowstats {S1,S2,Sv}; bn2 stats.
   B-frags direct from global Ut; in-place y1 (n-major) after barrier. */
__global__ __launch_bounds__(256) void k3_gnn(
    const float* __restrict__ corr, const float* __restrict__ bg,
    const float* __restrict__ agnn, float* __restrict__ ws)
{
  __shared__ float cwf[841];
  __shared__ unsigned short a_s[32*40];
  __shared__ float m1s[29], is1s[29], cms[29], st1s[29], st2s[29], svs[29];

  const int b = blockIdx.x, tid = threadIdx.x;
  const int wv = tid >> 6, lane = tid & 63;
  const int lrow = lane & 15, quad = lane >> 4;
  unsigned short* Utb = (unsigned short*)ws + (size_t)b * UTSTR;

  if (tid < 29) {
    m1s[tid] = ws[M1_OFF+tid]; is1s[tid] = ws[IS1_OFF+tid];
    st1s[tid] = 0.f; st2s[tid] = 0.f; svs[tid] = 0.f;
  }
  const float* cb = corr + (size_t)b * 841;
  for (int i = tid; i < 841; i += 256) cwf[i] = cb[i];
  __syncthreads();

  /* B frags from global (whole Ut[b] covered by 4 waves x 2 frags) */
  const int f0 = wv * 32;
  bf16x8 B0 = *(const bf16x8*)&Utb[(f0      + lrow)*32 + quad*8];
  bf16x8 B1 = *(const bf16x8*)&Utb[(f0 + 16 + lrow)*32 + quad*8];

  for (int i = tid; i < 1024; i += 256) {
    int n = i >> 5, m = i & 31;
    float v = (n < 29 && m < 29) ? cwf[n*29 + m] * is1s[m] : 0.f;
    a_s[n*40 + m] = f2bf(v);
  }
  if (tid < 29) {
    float cm = 0.f;
    for (int m = 0; m < 29; ++m) cm = fmaf(cwf[tid*29 + m] * is1s[m], m1s[m], cm);
    cms[tid] = cm;
  }
  __syncthreads();

  bf16x8 A0 = *(const bf16x8*)&a_s[lrow*40 + quad*8];
  bf16x8 A1 = *(const bf16x8*)&a_s[(16 + lrow)*40 + quad*8];
  f32x4 acc[2][2];
  acc[0][0] = (f32x4){0.f,0.f,0.f,0.f}; acc[0][1] = (f32x4){0.f,0.f,0.f,0.f};
  acc[1][0] = (f32x4){0.f,0.f,0.f,0.f}; acc[1][1] = (f32x4){0.f,0.f,0.f,0.f};
  acc[0][0] = __builtin_amdgcn_mfma_f32_16x16x32_bf16(A0, B0, acc[0][0], 0, 0, 0);
  acc[0][1] = __builtin_amdgcn_mfma_f32_16x16x32_bf16(A0, B1, acc[0][1], 0, 0, 0);
  acc[1][0] = __builtin_amdgcn_mfma_f32_16x16x32_bf16(A1, B0, acc[1][0], 0, 0, 0);
  acc[1][1] = __builtin_amdgcn_mfma_f32_16x16x32_bf16(A1, B1, acc[1][1], 0, 0, 0);
  __syncthreads();   /* all waves' Ut reads done -> in-place writes safe */

  const float ag = agnn[0];
  const float vA  = ws[V_OFF  + f0 + lrow],      vB  = ws[V_OFF  + f0 + 16 + lrow];
  const float csA = ws[CSW_OFF + f0 + lrow],     csB = ws[CSW_OFF + f0 + 16 + lrow];
  const float bgA = bg[f0 + lrow],               bgB = bg[f0 + 16 + lrow];
  #pragma unroll
  for (int mt = 0; mt < 2; ++mt) {
    #pragma unroll
    for (int i = 0; i < 4; ++i) {
      int n = mt*16 + quad*4 + i;
      if (n < 29) {
        float y0 = acc[mt][0][i] - cms[n]*csA + bgA;
        float y1 = acc[mt][1][i] - cms[n]*csB + bgB;
        y0 = (y0 >= 0.f) ? y0 : ag*y0;
        y1 = (y1 >= 0.f) ? y1 : ag*y1;
        Utb[n*D_ + f0 + lrow]      = f2bf(y0);
        Utb[n*D_ + f0 + 16 + lrow] = f2bf(y1);
        float sy  = y0 + y1;
        float sy2 = fmaf(y0, y0, y1*y1);
        float sv  = fmaf(y0, vA, y1*vB);
        #pragma unroll
        for (int off = 8; off >= 1; off >>= 1) {
          sy  += __shfl_xor(sy, off);
          sy2 += __shfl_xor(sy2, off);
          sv  += __shfl_xor(sv, off);
        }
        if (lrow == 0) {
          atomicAdd(&st1s[n], sy);
          atomicAdd(&st2s[n], sy2);
          atomicAdd(&svs[n],  sv);
        }
      }
    }
  }
  __syncthreads();
  if (tid < 29) {
    float* rs = (float*)(Utb + RS_SH);
    rs[tid]      = st1s[tid];
    rs[29 + tid] = st2s[tid];
    rs[58 + tid] = svs[tid];
    float* bn2 = ws + BN2_OFF + (size_t)(b & 31) * 58;
    atomicAdd(&bn2[tid*2+0], st1s[tid]);
    atomicAdd(&bn2[tid*2+1], st2s[tid]);
  }
}

__global__ void k3_finalize2(float* __restrict__ ws) {
  const int n = threadIdx.x; /* 32 */
  if (n < 29) {
    float s1 = 0.f, s2 = 0.f;
    for (int s = 0; s < 32; ++s) {
      s1 += ws[BN2_OFF + s*58 + n*2 + 0];
      s2 += ws[BN2_OFF + s*58 + n*2 + 1];
    }
    const float inv = 1.f / (float)(B_ * D_);
    float mean = s1 * inv, var = s2 * inv - mean * mean;
    ws[M2_OFF + n] = mean;
    ws[IS2_OFF + n] = rsqrtf(var + EPSBN);
  }
}

/* K4: rowstats -> softmax weights -> pooled = sum c_n y - koff -> @Wp + bp -> x3, bn3.
   4 waves = 4 b per block. */
__global__ __launch_bounds__(256) void k4_pool(
    const float* __restrict__ Wp, const float* __restrict__ bpv,
    float* __restrict__ ws)
{
  __shared__ float cs_s[4*32];
  __shared__ float pool_s[4*128];
  const int tid = threadIdx.x, wv = tid >> 6, lane = tid & 63;
  const int b = blockIdx.x * 4 + wv;
  const unsigned short* yb = (const unsigned short*)ws + (size_t)b * UTSTR;
  const float* rs = (const float*)(yb + RS_SH);
  const float V1 = ws[V1_OFF];

  float agg = -1e30f, m2 = 0.f, is2 = 0.f;
  if (lane < 29) {
    float S1 = rs[lane], S2 = rs[29+lane], Sv = rs[58+lane];
    m2 = ws[M2_OFF + lane]; is2 = ws[IS2_OFF + lane];
    float ss = fmaxf(S2 - 2.f*m2*S1 + 128.f*m2*m2, 0.f);
    float rn = sqrtf(ss);
    agg = (is2*(Sv - m2*V1)) / (is2*rn + 1e-8f);
  }
  float mx = agg;
  #pragma unroll
  for (int off = 32; off >= 1; off >>= 1) mx = fmaxf(mx, __shfl_xor(mx, off));
  float e = (lane < 29) ? __expf(agg - mx) : 0.f;
  float den = e, kof = e*is2*m2;
  #pragma unroll
  for (int off = 32; off >= 1; off >>= 1) { den += __shfl_xor(den, off); kof += __shfl_xor(kof, off); }
  float rden = 1.f / den;
  float koff = kof * rden;
  if (lane < 32) cs_s[wv*32 + lane] = (lane < 29) ? e*is2*rden : 0.f;
  __syncthreads();

  const unsigned* y32 = (const unsigned*)yb;
  float p0 = -koff, p1 = -koff;
  #pragma unroll
  for (int n = 0; n < 29; ++n) {
    float c = cs_s[wv*32 + n];
    unsigned u = y32[n*64 + lane];
    p0 = fmaf(c, bf2f(u & 0xffffu), p0);
    p1 = fmaf(c, bf2f(u >> 16), p1);
  }
  pool_s[wv*128 + 2*lane]     = p0;
  pool_s[wv*128 + 2*lane + 1] = p1;
  __syncthreads();

  float a0 = bpv[lane], a1 = bpv[64 + lane];
  const float* ps = pool_s + wv*128;
  #pragma unroll 4
  for (int j = 0; j < 128; ++j) {
    float p = ps[j];
    a0 = fmaf(p, Wp[j*D_ + lane], a0);
    a1 = fmaf(p, Wp[j*D_ + 64 + lane], a1);
  }
  ws[X3_OFF + (size_t)b*D_ + lane]      = a0;
  ws[X3_OFF + (size_t)b*D_ + 64 + lane] = a1;
  float* bn3 = ws + BN3_OFF + (size_t)(b & 31) * 256;
  atomicAdd(&bn3[lane*2+0], a0);
  atomicAdd(&bn3[lane*2+1], a0*a0);
  atomicAdd(&bn3[(64+lane)*2+0], a1);
  atomicAdd(&bn3[(64+lane)*2+1], a1*a1);
}

__global__ void k4_finalize3(float* __restrict__ ws) {
  const int k = threadIdx.x; /* 128 */
  float s1 = 0.f, s2 = 0.f;
  for (int s = 0; s < 32; ++s) {
    s1 += ws[BN3_OFF + s*256 + k*2 + 0];
    s2 += ws[BN3_OFF + s*256 + k*2 + 1];
  }
  const float inv = 1.f / (float)B_;
  float mean = s1 * inv, var = s2 * inv - mean * mean;
  ws[M3_OFF + k] = mean;
  ws[IS3_OFF + k] = rsqrtf(var + EPSBN);
}

/* K5: bn3 -> prelu(x@Wm1+bm1) -> sigmoid(h@Wm2+bm2) */
__global__ __launch_bounds__(128) void k5_mlp(
    const float* __restrict__ Wm1, const float* __restrict__ bm1,
    const float* __restrict__ amlp, const float* __restrict__ Wm2,
    const float* __restrict__ bm2, const float* __restrict__ ws,
    float* __restrict__ out)
{
  __shared__ float x_s[128];
  __shared__ float red[2];
  const int b = blockIdx.x, k = threadIdx.x;
  float x = (ws[X3_OFF + (size_t)b*D_ + k] - ws[M3_OFF + k]) * ws[IS3_OFF + k];
  x_s[k] = x;
  __syncthreads();
  float h = bm1[k];
  #pragma unroll 4
  for (int j = 0; j < 128; ++j) h = fmaf(x_s[j], Wm1[j*D_ + k], h);
  const float am = amlp[0];
  h = (h >= 0.f) ? h : am * h;
  float rr = h * Wm2[k];
  #pragma unroll
  for (int off = 32; off >= 1; off >>= 1) rr += __shfl_down(rr, off);
  if ((k & 63) == 0) red[k >> 6] = rr;
  __syncthreads();
  if (k == 0) {
    float logit = red[0] + red[1] + bm2[0];
    out[b] = 1.f / (1.f + expf(-logit));
  }
}

extern "C" void kernel_launch(void* const* d_in, const int* in_sizes, int n_in,
                              void* d_out, int out_size, void* d_ws, size_t ws_size,
                              hipStream_t stream)
{
  (void)in_sizes; (void)n_in; (void)out_size; (void)ws_size;
  const float* X    = (const float*)d_in[0];
  const float* corr = (const float*)d_in[1];
  const float* wc1  = (const float*)d_in[2];
  const float* bc1  = (const float*)d_in[3];
  const float* wc2  = (const float*)d_in[4];
  const float* bc2  = (const float*)d_in[5];
  const float* wc3  = (const float*)d_in[6];
  const float* bc3  = (const float*)d_in[7];
  const float* acnn = (const float*)d_in[8];
  const float* Wg   = (const float*)d_in[9];
  const float* bg   = (const float*)d_in[10];
  const float* agnn = (const float*)d_in[11];
  const float* cent = (const float*)d_in[12];
  const float* hw   = (const float*)d_in[13];
  const float* Wp   = (const float*)d_in[14];
  const float* bp   = (const float*)d_in[15];
  const float* Wm1  = (const float*)d_in[16];
  const float* bm1  = (const float*)d_in[17];
  const float* amlp = (const float*)d_in[18];
  const float* Wm2  = (const float*)d_in[19];
  const float* bm2  = (const float*)d_in[20];
  float* ws  = (float*)d_ws;
  float* out = (float*)d_out;

  hipMemsetAsync(ws + ACC_OFF, 0, 11904 * sizeof(float), stream);
  k0a_img<<<16, 256, 0, stream>>>(Wg, ws);
  k0b_cent<<<1, 128, 0, stream>>>(cent, hw, ws);
  k1_conv_gemm<<<ROWS/64, 512, 0, stream>>>(X, wc1, bc1, wc2, bc2, wc3, bc3, acnn, ws);
  k2_bn1<<<1, 32, 0, stream>>>(ws);
  k3_gnn<<<B_, 256, 0, stream>>>(corr, bg, agnn, ws);
  k3_finalize2<<<1, 32, 0, stream>>>(ws);
  k4_pool<<<B_/4, 256, 0, stream>>>(Wp, bp, ws);
  k4_finalize3<<<1, 128, 0, stream>>>(ws);
  k5_mlp<<<B_, 128, 0, stream>>>(Wm1, bm1, amlp, Wm2, bm2, ws, out);
}

// Round 4
// 530.468 us; speedup vs baseline: 1.8641x; 1.1772x over previous
//
#include <hip/hip_runtime.h>

#define B_    8192
#define N_    29
#define F_    147
#define DC    429
#define D_    128
#define ROWS  (B_*N_)          /* 237568 */
#define EPSBN 1e-5f

/* Ut: per-b 4096 shorts: [f:128][m:32] bf16, m=29..31 zero; y1 overwrites in-place
   as [n:29][d:128] bf16 (3712 shorts); rowstats (29*3 fp32) at short-offset 3712. */
#define UTSTR   4096                        /* shorts per b */
#define RS_SH   3712                        /* short offset of rowstats */

/* ws layout in float units */
#define X3_OFF   16777216                   /* fp32 B_*128 */
#define ACC_OFF  (X3_OFF + B_*D_)           /* 17825792 */
#define BN1_OFF  (ACC_OFF)                  /* 32*29*2 */
#define BN2_OFF  (ACC_OFF + 1856)
#define BN3_OFF  (ACC_OFF + 3712)           /* 32*128*2 */
#define FIN_OFF  (ACC_OFF + 11904)
#define M1_OFF   (FIN_OFF + 0)
#define IS1_OFF  (FIN_OFF + 32)
#define M2_OFF   (FIN_OFF + 64)
#define IS2_OFF  (FIN_OFF + 96)
#define M3_OFF   (FIN_OFF + 128)
#define IS3_OFF  (FIN_OFF + 256)
#define CSW_OFF  (FIN_OFF + 384)
#define V_OFF    (FIN_OFF + 512)
#define V1_OFF   (FIN_OFF + 640)
#define IMG_OFF  (FIN_OFF + 1024)           /* bf16 Wg image: 128*448 shorts n-major */

typedef __bf16 bf16x8 __attribute__((ext_vector_type(8)));
typedef float  f32x4  __attribute__((ext_vector_type(4)));

__device__ __forceinline__ unsigned short f2bf(float f) {
  unsigned int u = __float_as_uint(f);
  u += 0x7fffu + ((u >> 16) & 1u);
  return (unsigned short)(u >> 16);
}
__device__ __forceinline__ float bf2f(unsigned u16) {
  return __uint_as_float(u16 << 16);
}

#define TSTR 456   /* 448+8 shorts: 4-bank rotation per row */
#define UTILS 34   /* epilogue LDS tile stride (shorts): odd*17 banks, conflict-free */

/* K0a: build bf16 Wg image, n-major [128][448], rows shifted to t-layout
   (dk: 0..144 conv1, 145 pad, 146..288 conv2, 289 pad, 290..430 conv3, 431..447 pad);
   also colsum(Wg). grid 16 x 256. */
__global__ void k0a_img(const float* __restrict__ Wg, float* __restrict__ ws)
{
  __shared__ float cs_l[8];
  const int tid = threadIdx.x;
  const int kb = blockIdx.x * 8;
  if (tid < 8) cs_l[tid] = 0.f;
  __syncthreads();
  unsigned short* img = (unsigned short*)(ws + IMG_OFF);
  for (int i = tid; i < 8*448; i += 256) {
    int kk = i / 448, dk = i - kk*448;
    int k = kb + kk;
    int d;
    if      (dk < 145)  d = dk;
    else if (dk == 145) d = -1;
    else if (dk < 289)  d = dk - 1;
    else if (dk == 289) d = -1;
    else if (dk < 431)  d = dk - 2;
    else                d = -1;
    float v = (d >= 0) ? Wg[(size_t)d*D_ + k] : 0.f;
    img[(size_t)k*448 + dk] = f2bf(v);
    if (d >= 0) atomicAdd(&cs_l[kk], v);
  }
  __syncthreads();
  if (tid < 8) ws[CSW_OFF + kb + tid] = cs_l[tid];
}

/* K0b: v = sum_h hw[h]*normalize(cent[h]); V1 = sum(v). 1 x 128 */
__global__ void k0b_cent(const float* __restrict__ cent, const float* __restrict__ hw,
                         float* __restrict__ ws)
{
  __shared__ float sq[128];
  __shared__ float nrm;
  const int tid = threadIdx.x;
  float vk = 0.f;
  for (int h = 0; h < 4; ++h) {
    float c = cent[h*D_ + tid];
    sq[tid] = c*c;
    __syncthreads();
    if (tid == 0) { float s=0.f; for (int j=0;j<128;++j) s+=sq[j]; nrm = sqrtf(s)+1e-8f; }
    __syncthreads();
    vk += hw[h] * c / nrm;
    __syncthreads();
  }
  ws[V_OFF + tid] = vk;
  sq[tid] = vk;
  __syncthreads();
  if (tid == 0) { float s=0.f; for (int j=0;j<128;++j) s+=sq[j]; ws[V1_OFF] = s; }
}

/* K1: one b per block (29 rows pad to 32). Conv+prelu -> t_s; bn1 stats via shuffle;
   MFMA with B preloaded in registers; coalesced Ut store via LDS transpose tile. */
__global__ __launch_bounds__(512, 4) void k1_conv_gemm(
    const float* __restrict__ X,
    const float* __restrict__ wc1, const float* __restrict__ bc1,
    const float* __restrict__ wc2, const float* __restrict__ bc2,
    const float* __restrict__ wc3, const float* __restrict__ bc3,
    const float* __restrict__ acnn, float* __restrict__ ws)
{
  __shared__ unsigned short t_s[32*TSTR];          /* 29184 B */
  __shared__ __align__(16) float xs[4272];         /* 17088 B; reused as Ut tile (8704B) */
  const int tid = threadIdx.x;
  const int b = blockIdx.x;

  /* zero: rows 29..31 full (3*456) + pad cols of rows 0..28 (19 each) */
  for (int i = tid; i < 3*456; i += 512) t_s[29*TSTR + i] = 0;
  for (int i = tid; i < 29*19; i += 512) {
    int r = i / 19, j = i - r*19;
    int col = (j == 0) ? 145 : ((j == 1) ? 289 : (429 + j));
    t_s[r*TSTR + col] = 0;
  }

  const float c10 = wc1[0], c11 = wc1[1], c12 = wc1[2], b1 = bc1[0];
  const float c20 = wc2[0], c21 = wc2[1], c22 = wc2[2], c23 = wc2[3], c24 = wc2[4], b2 = bc2[0];
  const float c30 = wc3[0], c31 = wc3[1], c32 = wc3[2], c33 = wc3[3], c34 = wc3[4],
              c35 = wc3[5], c36 = wc3[6], b3 = bc3[0];
  const float ap = acnn[0];

  /* stage X rows for this b */
  {
    const float* xsrc = X + (size_t)b * N_ * F_;
    for (int i = tid; i < N_*F_; i += 512) xs[i] = xsrc[i];
  }
  __syncthreads();

  /* conv: r = tid>>4 (row), q = tid&15, f0 = q*10 (q<15 active, covers 0..144) */
  {
    const int r = tid >> 4, q = tid & 15;
    const int f0 = q * 10;
    float s1 = 0.f, s2 = 0.f;
    if (r < N_ && q < 15) {
      const int cnt = min(10, 145 - f0);
      const int n2 = min(cnt, 143 - f0);
      const int n3 = min(cnt, 141 - f0);
      const float* xr = xs + r*F_;
      unsigned short* tr = t_s + r*TSTR;
      unsigned int* tr32 = (unsigned int*)tr;
      float wA=xr[f0],wB=xr[f0+1],wC=xr[f0+2],wD=xr[f0+3],wE=xr[f0+4],wF=xr[f0+5],wG;
      float o1[10], o2[10], o3[10];
      #pragma unroll
      for (int i2 = 0; i2 < 10; ++i2) {
        if (i2 < cnt) {
          int f = f0 + i2;
          wG = (f + 6 < F_) ? xr[f+6] : 0.f;
          float v1 = fmaf(wA,c10, fmaf(wB,c11, fmaf(wC,c12, b1)));
          v1 = (v1 >= 0.f) ? v1 : ap*v1;
          float v2 = fmaf(wA,c20, fmaf(wB,c21, fmaf(wC,c22, fmaf(wD,c23, fmaf(wE,c24, b2)))));
          v2 = (v2 >= 0.f) ? v2 : ap*v2;
          float v3 = fmaf(wA,c30, fmaf(wB,c31, fmaf(wC,c32, fmaf(wD,c33, fmaf(wE,c34, fmaf(wF,c35, fmaf(wG,c36, b3)))))));
          v3 = (v3 >= 0.f) ? v3 : ap*v3;
          o1[i2] = v1; o2[i2] = v2; o3[i2] = v3;
          s1 += v1; s2 = fmaf(v1, v1, s2);
          if (i2 < n2) { s1 += v2; s2 = fmaf(v2, v2, s2); }
          if (i2 < n3) { s1 += v3; s2 = fmaf(v3, v3, s2); }
          wA=wB; wB=wC; wC=wD; wD=wE; wE=wF; wF=wG;
        }
      }
      #pragma unroll
      for (int i2 = 0; i2 < 10; i2 += 2) {
        if (i2+1 < cnt)     tr32[(f0+i2)>>1] = (unsigned)f2bf(o1[i2]) | ((unsigned)f2bf(o1[i2+1])<<16);
        else if (i2 < cnt)  tr[f0+i2] = f2bf(o1[i2]);
        if (i2+1 < n2)      tr32[(146+f0+i2)>>1] = (unsigned)f2bf(o2[i2]) | ((unsigned)f2bf(o2[i2+1])<<16);
        else if (i2 < n2)   tr[146+f0+i2] = f2bf(o2[i2]);
        if (i2+1 < n3)      tr32[(290+f0+i2)>>1] = (unsigned)f2bf(o3[i2]) | ((unsigned)f2bf(o3[i2+1])<<16);
        else if (i2 < n3)   tr[290+f0+i2] = f2bf(o3[i2]);
      }
    }
    /* reduce s1,s2 over the 16 q-lanes (xor <=15 stays in group) */
    #pragma unroll
    for (int off = 8; off >= 1; off >>= 1) {
      s1 += __shfl_xor(s1, off);
      s2 += __shfl_xor(s2, off);
    }
    if (r < N_ && q == 0) {
      float* bn1 = ws + BN1_OFF + (size_t)(b & 31) * 58;
      atomicAdd(&bn1[r*2+0], s1);
      atomicAdd(&bn1[r*2+1], s2);
    }
  }

  /* B preload: wave wv owns n-tile n0 = wv*16; 14 frags in registers */
  const int wv = tid >> 6, lane = tid & 63;
  const int lrow = lane & 15, quad = lane >> 4;
  const int n0 = wv * 16;
  const unsigned short* imgp = (const unsigned short*)(ws + IMG_OFF);
  const unsigned short* gB = imgp + (size_t)(n0 + lrow)*448 + quad*8;
  bf16x8 Bf[14];
  #pragma unroll
  for (int ks = 0; ks < 14; ++ks) Bf[ks] = *(const bf16x8*)(gB + ks*32);

  __syncthreads();   /* t_s complete */

  f32x4 acc0 = (f32x4){0.f,0.f,0.f,0.f};
  f32x4 acc1 = (f32x4){0.f,0.f,0.f,0.f};
  #pragma unroll
  for (int ks = 0; ks < 14; ++ks) {
    const int k0 = ks * 32;
    bf16x8 A0 = *(const bf16x8*)&t_s[(lrow)*TSTR      + k0 + quad*8];
    bf16x8 A1 = *(const bf16x8*)&t_s[(16 + lrow)*TSTR + k0 + quad*8];
    acc0 = __builtin_amdgcn_mfma_f32_16x16x32_bf16(A0, Bf[ks], acc0, 0, 0, 0);
    acc1 = __builtin_amdgcn_mfma_f32_16x16x32_bf16(A1, Bf[ks], acc1, 0, 0, 0);
  }

  /* epilogue: acc -> LDS Ut tile [f:128][m:32+pad2] -> coalesced u32 store */
  __syncthreads();   /* xs conv reads done; safe to reuse as utile */
  unsigned short* utile = (unsigned short*)xs;
  {
    const int f = n0 + lrow;
    #pragma unroll
    for (int i = 0; i < 4; ++i) {
      utile[f*UTILS + quad*4 + i]      = f2bf(acc0[i]);
      utile[f*UTILS + 16 + quad*4 + i] = f2bf(acc1[i]);
    }
  }
  __syncthreads();
  {
    unsigned* Ug = (unsigned*)((unsigned short*)ws + (size_t)b * UTSTR);
    const unsigned* u32t = (const unsigned*)utile;
    #pragma unroll
    for (int it = 0; it < 4; ++it) {
      int idx = tid + it*512;
      int f = idx >> 4, pr = idx & 15;
      Ug[f*16 + pr] = u32t[f*17 + pr];
    }
  }
}

/* K2: finalize bn1 */
__global__ void k2_bn1(float* __restrict__ ws) {
  const int k = threadIdx.x; /* 32 */
  if (k < 29) {
    float s1 = 0.f, s2 = 0.f;
    for (int s = 0; s < 32; ++s) {
      s1 += ws[BN1_OFF + s*58 + k*2 + 0];
      s2 += ws[BN1_OFF + s*58 + k*2 + 1];
    }
    const float inv = 1.f / (float)(B_ * DC);
    float mean = s1 * inv;
    float var  = s2 * inv - mean * mean;
    ws[M1_OFF  + k] = mean;
    ws[IS1_OFF + k] = rsqrtf(var + EPSBN);
  }
}

/* K3: y1 = prelu(corr@bn1(t)@Wg + bg); per-(b,n) rowstats {S1,S2,Sv}; bn2 stats. */
__global__ __launch_bounds__(256) void k3_gnn(
    const float* __restrict__ corr, const float* __restrict__ bg,
    const float* __restrict__ agnn, float* __restrict__ ws)
{
  __shared__ float cwf[841];
  __shared__ unsigned short a_s[32*40];
  __shared__ float m1s[29], is1s[29], cms[29], st1s[29], st2s[29], svs[29];

  const int b = blockIdx.x, tid = threadIdx.x;
  const int wv = tid >> 6, lane = tid & 63;
  const int lrow = lane & 15, quad = lane >> 4;
  unsigned short* Utb = (unsigned short*)ws + (size_t)b * UTSTR;

  if (tid < 29) {
    m1s[tid] = ws[M1_OFF+tid]; is1s[tid] = ws[IS1_OFF+tid];
    st1s[tid] = 0.f; st2s[tid] = 0.f; svs[tid] = 0.f;
  }
  const float* cb = corr + (size_t)b * 841;
  for (int i = tid; i < 841; i += 256) cwf[i] = cb[i];
  __syncthreads();

  const int f0 = wv * 32;
  bf16x8 B0 = *(const bf16x8*)&Utb[(f0      + lrow)*32 + quad*8];
  bf16x8 B1 = *(const bf16x8*)&Utb[(f0 + 16 + lrow)*32 + quad*8];

  for (int i = tid; i < 1024; i += 256) {
    int n = i >> 5, m = i & 31;
    float v = (n < 29 && m < 29) ? cwf[n*29 + m] * is1s[m] : 0.f;
    a_s[n*40 + m] = f2bf(v);
  }
  if (tid < 29) {
    float cm = 0.f;
    for (int m = 0; m < 29; ++m) cm = fmaf(cwf[tid*29 + m] * is1s[m], m1s[m], cm);
    cms[tid] = cm;
  }
  __syncthreads();

  bf16x8 A0 = *(const bf16x8*)&a_s[lrow*40 + quad*8];
  bf16x8 A1 = *(const bf16x8*)&a_s[(16 + lrow)*40 + quad*8];
  f32x4 acc[2][2];
  acc[0][0] = (f32x4){0.f,0.f,0.f,0.f}; acc[0][1] = (f32x4){0.f,0.f,0.f,0.f};
  acc[1][0] = (f32x4){0.f,0.f,0.f,0.f}; acc[1][1] = (f32x4){0.f,0.f,0.f,0.f};
  acc[0][0] = __builtin_amdgcn_mfma_f32_16x16x32_bf16(A0, B0, acc[0][0], 0, 0, 0);
  acc[0][1] = __builtin_amdgcn_mfma_f32_16x16x32_bf16(A0, B1, acc[0][1], 0, 0, 0);
  acc[1][0] = __builtin_amdgcn_mfma_f32_16x16x32_bf16(A1, B0, acc[1][0], 0, 0, 0);
  acc[1][1] = __builtin_amdgcn_mfma_f32_16x16x32_bf16(A1, B1, acc[1][1], 0, 0, 0);
  __syncthreads();   /* all waves' Ut reads done -> in-place writes safe */

  const float ag = agnn[0];
  const float vA  = ws[V_OFF  + f0 + lrow],      vB  = ws[V_OFF  + f0 + 16 + lrow];
  const float csA = ws[CSW_OFF + f0 + lrow],     csB = ws[CSW_OFF + f0 + 16 + lrow];
  const float bgA = bg[f0 + lrow],               bgB = bg[f0 + 16 + lrow];
  #pragma unroll
  for (int mt = 0; mt < 2; ++mt) {
    #pragma unroll
    for (int i = 0; i < 4; ++i) {
      int n = mt*16 + quad*4 + i;
      if (n < 29) {
        float y0 = acc[mt][0][i] - cms[n]*csA + bgA;
        float y1 = acc[mt][1][i] - cms[n]*csB + bgB;
        y0 = (y0 >= 0.f) ? y0 : ag*y0;
        y1 = (y1 >= 0.f) ? y1 : ag*y1;
        Utb[n*D_ + f0 + lrow]      = f2bf(y0);
        Utb[n*D_ + f0 + 16 + lrow] = f2bf(y1);
        float sy  = y0 + y1;
        float sy2 = fmaf(y0, y0, y1*y1);
        float sv  = fmaf(y0, vA, y1*vB);
        #pragma unroll
        for (int off = 8; off >= 1; off >>= 1) {
          sy  += __shfl_xor(sy, off);
          sy2 += __shfl_xor(sy2, off);
          sv  += __shfl_xor(sv, off);
        }
        if (lrow == 0) {
          atomicAdd(&st1s[n], sy);
          atomicAdd(&st2s[n], sy2);
          atomicAdd(&svs[n],  sv);
        }
      }
    }
  }
  __syncthreads();
  if (tid < 29) {
    float* rs = (float*)(Utb + RS_SH);
    rs[tid]      = st1s[tid];
    rs[29 + tid] = st2s[tid];
    rs[58 + tid] = svs[tid];
    float* bn2 = ws + BN2_OFF + (size_t)(b & 31) * 58;
    atomicAdd(&bn2[tid*2+0], st1s[tid]);
    atomicAdd(&bn2[tid*2+1], st2s[tid]);
  }
}

__global__ void k3_finalize2(float* __restrict__ ws) {
  const int n = threadIdx.x; /* 32 */
  if (n < 29) {
    float s1 = 0.f, s2 = 0.f;
    for (int s = 0; s < 32; ++s) {
      s1 += ws[BN2_OFF + s*58 + n*2 + 0];
      s2 += ws[BN2_OFF + s*58 + n*2 + 1];
    }
    const float inv = 1.f / (float)(B_ * D_);
    float mean = s1 * inv, var = s2 * inv - mean * mean;
    ws[M2_OFF + n] = mean;
    ws[IS2_OFF + n] = rsqrtf(var + EPSBN);
  }
}

/* K4: rowstats -> softmax weights -> pooled -> @Wp + bp -> x3, bn3. 4 b per block. */
__global__ __launch_bounds__(256) void k4_pool(
    const float* __restrict__ Wp, const float* __restrict__ bpv,
    float* __restrict__ ws)
{
  __shared__ float cs_s[4*32];
  __shared__ float pool_s[4*128];
  const int tid = threadIdx.x, wv = tid >> 6, lane = tid & 63;
  const int b = blockIdx.x * 4 + wv;
  const unsigned short* yb = (const unsigned short*)ws + (size_t)b * UTSTR;
  const float* rs = (const float*)(yb + RS_SH);
  const float V1 = ws[V1_OFF];

  float agg = -1e30f, m2 = 0.f, is2 = 0.f;
  if (lane < 29) {
    float S1 = rs[lane], S2 = rs[29+lane], Sv = rs[58+lane];
    m2 = ws[M2_OFF + lane]; is2 = ws[IS2_OFF + lane];
    float ss = fmaxf(S2 - 2.f*m2*S1 + 128.f*m2*m2, 0.f);
    float rn = sqrtf(ss);
    agg = (is2*(Sv - m2*V1)) / (is2*rn + 1e-8f);
  }
  float mx = agg;
  #pragma unroll
  for (int off = 32; off >= 1; off >>= 1) mx = fmaxf(mx, __shfl_xor(mx, off));
  float e = (lane < 29) ? __expf(agg - mx) : 0.f;
  float den = e, kof = e*is2*m2;
  #pragma unroll
  for (int off = 32; off >= 1; off >>= 1) { den += __shfl_xor(den, off); kof += __shfl_xor(kof, off); }
  float rden = 1.f / den;
  float koff = kof * rden;
  if (lane < 32) cs_s[wv*32 + lane] = (lane < 29) ? e*is2*rden : 0.f;
  __syncthreads();

  const unsigned* y32 = (const unsigned*)yb;
  float p0 = -koff, p1 = -koff;
  #pragma unroll
  for (int n = 0; n < 29; ++n) {
    float c = cs_s[wv*32 + n];
    unsigned u = y32[n*64 + lane];
    p0 = fmaf(c, bf2f(u & 0xffffu), p0);
    p1 = fmaf(c, bf2f(u >> 16), p1);
  }
  pool_s[wv*128 + 2*lane]     = p0;
  pool_s[wv*128 + 2*lane + 1] = p1;
  __syncthreads();

  float a0 = bpv[lane], a1 = bpv[64 + lane];
  const float* ps = pool_s + wv*128;
  #pragma unroll 4
  for (int j = 0; j < 128; ++j) {
    float p = ps[j];
    a0 = fmaf(p, Wp[j*D_ + lane], a0);
    a1 = fmaf(p, Wp[j*D_ + 64 + lane], a1);
  }
  ws[X3_OFF + (size_t)b*D_ + lane]      = a0;
  ws[X3_OFF + (size_t)b*D_ + 64 + lane] = a1;
  float* bn3 = ws + BN3_OFF + (size_t)(b & 31) * 256;
  atomicAdd(&bn3[lane*2+0], a0);
  atomicAdd(&bn3[lane*2+1], a0*a0);
  atomicAdd(&bn3[(64+lane)*2+0], a1);
  atomicAdd(&bn3[(64+lane)*2+1], a1*a1);
}

__global__ void k4_finalize3(float* __restrict__ ws) {
  const int k = threadIdx.x; /* 128 */
  float s1 = 0.f, s2 = 0.f;
  for (int s = 0; s < 32; ++s) {
    s1 += ws[BN3_OFF + s*256 + k*2 + 0];
    s2 += ws[BN3_OFF + s*256 + k*2 + 1];
  }
  const float inv = 1.f / (float)B_;
  float mean = s1 * inv, var = s2 * inv - mean * mean;
  ws[M3_OFF + k] = mean;
  ws[IS3_OFF + k] = rsqrtf(var + EPSBN);
}

/* K5: bn3 -> prelu(x@Wm1+bm1) -> sigmoid(h@Wm2+bm2) */
__global__ __launch_bounds__(128) void k5_mlp(
    const float* __restrict__ Wm1, const float* __restrict__ bm1,
    const float* __restrict__ amlp, const float* __restrict__ Wm2,
    const float* __restrict__ bm2, const float* __restrict__ ws,
    float* __restrict__ out)
{
  __shared__ float x_s[128];
  __shared__ float red[2];
  const int b = blockIdx.x, k = threadIdx.x;
  float x = (ws[X3_OFF + (size_t)b*D_ + k] - ws[M3_OFF + k]) * ws[IS3_OFF + k];
  x_s[k] = x;
  __syncthreads();
  float h = bm1[k];
  #pragma unroll 4
  for (int j = 0; j < 128; ++j) h = fmaf(x_s[j], Wm1[j*D_ + k], h);
  const float am = amlp[0];
  h = (h >= 0.f) ? h : am * h;
  float rr = h * Wm2[k];
  #pragma unroll
  for (int off = 32; off >= 1; off >>= 1) rr += __shfl_down(rr, off);
  if ((k & 63) == 0) red[k >> 6] = rr;
  __syncthreads();
  if (k == 0) {
    float logit = red[0] + red[1] + bm2[0];
    out[b] = 1.f / (1.f + expf(-logit));
  }
}

extern "C" void kernel_launch(void* const* d_in, const int* in_sizes, int n_in,
                              void* d_out, int out_size, void* d_ws, size_t ws_size,
                              hipStream_t stream)
{
  (void)in_sizes; (void)n_in; (void)out_size; (void)ws_size;
  const float* X    = (const float*)d_in[0];
  const float* corr = (const float*)d_in[1];
  const float* wc1  = (const float*)d_in[2];
  const float* bc1  = (const float*)d_in[3];
  const float* wc2  = (const float*)d_in[4];
  const float* bc2  = (const float*)d_in[5];
  const float* wc3  = (const float*)d_in[6];
  const float* bc3  = (const float*)d_in[7];
  const float* acnn = (const float*)d_in[8];
  const float* Wg   = (const float*)d_in[9];
  const float* bg   = (const float*)d_in[10];
  const float* agnn = (const float*)d_in[11];
  const float* cent = (const float*)d_in[12];
  const float* hw   = (const float*)d_in[13];
  const float* Wp   = (const float*)d_in[14];
  const float* bp   = (const float*)d_in[15];
  const float* Wm1  = (const float*)d_in[16];
  const float* bm1  = (const float*)d_in[17];
  const float* amlp = (const float*)d_in[18];
  const float* Wm2  = (const float*)d_in[19];
  const float* bm2  = (const float*)d_in[20];
  float* ws  = (float*)d_ws;
  float* out = (float*)d_out;

  hipMemsetAsync(ws + ACC_OFF, 0, 11904 * sizeof(float), stream);
  k0a_img<<<16, 256, 0, stream>>>(Wg, ws);
  k0b_cent<<<1, 128, 0, stream>>>(cent, hw, ws);
  k1_conv_gemm<<<B_, 512, 0, stream>>>(X, wc1, bc1, wc2, bc2, wc3, bc3, acnn, ws);
  k2_bn1<<<1, 32, 0, stream>>>(ws);
  k3_gnn<<<B_, 256, 0, stream>>>(corr, bg, agnn, ws);
  k3_finalize2<<<1, 32, 0, stream>>>(ws);
  k4_pool<<<B_/4, 256, 0, stream>>>(Wp, bp, ws);
  k4_finalize3<<<1, 128, 0, stream>>>(ws);
  k5_mlp<<<B_, 128, 0, stream>>>(Wm1, bm1, amlp, Wm2, bm2, ws, out);
}

// Round 5
// 492.672 us; speedup vs baseline: 2.0071x; 1.0767x over previous
//
#include <hip/hip_runtime.h>

#define B_    8192
#define N_    29
#define F_    147
#define DC    429
#define D_    128
#define ROWS  (B_*N_)          /* 237568 */
#define EPSBN 1e-5f

/* Ut: per-b 4096 shorts: [f:128][m:32] bf16, m=29..31 zero; y1 overwrites in-place
   as [n:29][d:128] bf16 (3712 shorts); rowstats (29*3 fp32) at short-offset 3712. */
#define UTSTR   4096                        /* shorts per b */
#define RS_SH   3712                        /* short offset of rowstats */

/* ws layout in float units */
#define X3_OFF   16777216                   /* fp32 B_*128 */
#define ACC_OFF  (X3_OFF + B_*D_)           /* 17825792 */
#define BN1_OFF  (ACC_OFF)                  /* 32*29*2 */
#define BN2_OFF  (ACC_OFF + 1856)
#define BN3_OFF  (ACC_OFF + 3712)           /* 32*128*2 */
#define FIN_OFF  (ACC_OFF + 11904)
#define M1_OFF   (FIN_OFF + 0)
#define IS1_OFF  (FIN_OFF + 32)
#define M2_OFF   (FIN_OFF + 64)
#define IS2_OFF  (FIN_OFF + 96)
#define M3_OFF   (FIN_OFF + 128)
#define IS3_OFF  (FIN_OFF + 256)
#define CSW_OFF  (FIN_OFF + 384)
#define V_OFF    (FIN_OFF + 512)
#define V1_OFF   (FIN_OFF + 640)
#define IMG_OFF  (FIN_OFF + 1024)           /* bf16 Wg image: 128*448 shorts n-major */

typedef __bf16 bf16x8 __attribute__((ext_vector_type(8)));
typedef float  f32x4  __attribute__((ext_vector_type(4)));

__device__ __forceinline__ unsigned short f2bf(float f) {
  unsigned int u = __float_as_uint(f);
  u += 0x7fffu + ((u >> 16) & 1u);
  return (unsigned short)(u >> 16);
}
__device__ __forceinline__ float bf2f(unsigned u16) {
  return __uint_as_float(u16 << 16);
}

#define TSTR 456   /* 448+8 shorts */
#define UTILS 34   /* epilogue LDS tile stride (shorts) */

/* K0a: bf16 Wg image, n-major [128][448], rows in t-layout; colsum(Wg). */
__global__ void k0a_img(const float* __restrict__ Wg, float* __restrict__ ws)
{
  __shared__ float cs_l[8];
  const int tid = threadIdx.x;
  const int kb = blockIdx.x * 8;
  if (tid < 8) cs_l[tid] = 0.f;
  __syncthreads();
  unsigned short* img = (unsigned short*)(ws + IMG_OFF);
  for (int i = tid; i < 8*448; i += 256) {
    int kk = i / 448, dk = i - kk*448;
    int k = kb + kk;
    int d;
    if      (dk < 145)  d = dk;
    else if (dk == 145) d = -1;
    else if (dk < 289)  d = dk - 1;
    else if (dk == 289) d = -1;
    else if (dk < 431)  d = dk - 2;
    else                d = -1;
    float v = (d >= 0) ? Wg[(size_t)d*D_ + k] : 0.f;
    img[(size_t)k*448 + dk] = f2bf(v);
    if (d >= 0) atomicAdd(&cs_l[kk], v);
  }
  __syncthreads();
  if (tid < 8) ws[CSW_OFF + kb + tid] = cs_l[tid];
}

/* K0b: v = sum_h hw[h]*normalize(cent[h]); V1 = sum(v). */
__global__ void k0b_cent(const float* __restrict__ cent, const float* __restrict__ hw,
                         float* __restrict__ ws)
{
  __shared__ float sq[128];
  __shared__ float nrm;
  const int tid = threadIdx.x;
  float vk = 0.f;
  for (int h = 0; h < 4; ++h) {
    float c = cent[h*D_ + tid];
    sq[tid] = c*c;
    __syncthreads();
    if (tid == 0) { float s=0.f; for (int j=0;j<128;++j) s+=sq[j]; nrm = sqrtf(s)+1e-8f; }
    __syncthreads();
    vk += hw[h] * c / nrm;
    __syncthreads();
  }
  ws[V_OFF + tid] = vk;
  sq[tid] = vk;
  __syncthreads();
  if (tid == 0) { float s=0.f; for (int j=0;j<128;++j) s+=sq[j]; ws[V1_OFF] = s; }
}

/* K1: TWO b per block, 512 threads / 8 waves (bb = wv>>2, col-group = wv&3).
   Conv direct-from-global sliding window -> ds_write_b16 to t_s (no arrays).
   MFMA: B-pair prefetched 1 ks ahead, 4 MFMAs per pair. utile aliases t_s. */
__global__ __launch_bounds__(512, 2) void k1_conv_gemm(
    const float* __restrict__ X,
    const float* __restrict__ wc1, const float* __restrict__ bc1,
    const float* __restrict__ wc2, const float* __restrict__ bc2,
    const float* __restrict__ wc3, const float* __restrict__ bc3,
    const float* __restrict__ acnn, float* __restrict__ ws)
{
  __shared__ __align__(16) unsigned short t_s[64*TSTR];   /* 58368 B; aliased by utile later */
  const int tid = threadIdx.x;
  const int b0 = blockIdx.x * 2;

  /* zero pads: rows n=29..31 of each bb full 448; pad cols of active rows */
  for (int i = tid; i < 2*3*448; i += 512) {
    int bb = i / (3*448), rem = i - bb*(3*448);
    int r = rem / 448, c = rem - r*448;
    t_s[(bb*32 + 29 + r)*TSTR + c] = 0;
  }
  for (int i = tid; i < 58*19; i += 512) {
    int rr = i / 19, j = i - rr*19;
    int bb = (rr >= 29), n = rr - bb*29;
    int col = (j == 0) ? 145 : ((j == 1) ? 289 : (429 + j));
    t_s[(bb*32 + n)*TSTR + col] = 0;
  }

  const float c10 = wc1[0], c11 = wc1[1], c12 = wc1[2], b1 = bc1[0];
  const float c20 = wc2[0], c21 = wc2[1], c22 = wc2[2], c23 = wc2[3], c24 = wc2[4], b2 = bc2[0];
  const float c30 = wc3[0], c31 = wc3[1], c32 = wc3[2], c33 = wc3[3], c34 = wc3[4],
              c35 = wc3[5], c36 = wc3[6], b3 = bc3[0];
  const float ap = acnn[0];

  /* conv: r = tid>>3 in 0..63 (maps bb = r>>5, n = r&31), q = tid&7, f0 = q*19 */
  {
    const int r = tid >> 3, q = tid & 7;
    const int bb = r >> 5, n = r & 31;
    const int f0 = q * 19;
    float s1 = 0.f, s2 = 0.f;
    const bool act = (n < 29);
    if (act) {
      const int cnt = min(19, 145 - f0);          /* q<7: 19, q==7: 12 */
      const int n2 = min(cnt, 143 - f0);
      const int n3 = min(cnt, 141 - f0);
      const float* xr = X + (size_t)((b0 + bb)*N_ + n) * F_;
      unsigned short* tr = t_s + (bb*32 + n)*TSTR;
      float wA=xr[f0],wB=xr[f0+1],wC=xr[f0+2],wD=xr[f0+3],wE=xr[f0+4],wF=xr[f0+5],wG;
      #pragma unroll
      for (int i2 = 0; i2 < 19; ++i2) {
        if (i2 < cnt) {
          int f = f0 + i2;
          wG = (f + 6 < F_) ? xr[f+6] : 0.f;
          float v1 = fmaf(wA,c10, fmaf(wB,c11, fmaf(wC,c12, b1)));
          v1 = (v1 >= 0.f) ? v1 : ap*v1;
          s1 += v1; s2 = fmaf(v1, v1, s2);
          tr[f] = f2bf(v1);
          if (i2 < n2) {
            float v2 = fmaf(wA,c20, fmaf(wB,c21, fmaf(wC,c22, fmaf(wD,c23, fmaf(wE,c24, b2)))));
            v2 = (v2 >= 0.f) ? v2 : ap*v2;
            s1 += v2; s2 = fmaf(v2, v2, s2);
            tr[146+f] = f2bf(v2);
          }
          if (i2 < n3) {
            float v3 = fmaf(wA,c30, fmaf(wB,c31, fmaf(wC,c32, fmaf(wD,c33, fmaf(wE,c34, fmaf(wF,c35, fmaf(wG,c36, b3)))))));
            v3 = (v3 >= 0.f) ? v3 : ap*v3;
            s1 += v3; s2 = fmaf(v3, v3, s2);
            tr[290+f] = f2bf(v3);
          }
          wA=wB; wB=wC; wC=wD; wD=wE; wE=wF; wF=wG;
        }
      }
    }
    /* reduce over the 8 q-lanes of this row */
    #pragma unroll
    for (int off = 4; off >= 1; off >>= 1) {
      s1 += __shfl_xor(s1, off);
      s2 += __shfl_xor(s2, off);
    }
    if (act && q == 0) {
      float* bn1 = ws + BN1_OFF + (size_t)(blockIdx.x & 31) * 58;
      atomicAdd(&bn1[n*2+0], s1);
      atomicAdd(&bn1[n*2+1], s2);
    }
  }
  __syncthreads();

  /* MFMA: wave wv: bb = wv>>2, col tile n0 = (wv&3)*32 */
  const int wv = tid >> 6, lane = tid & 63;
  const int lrow = lane & 15, quad = lane >> 4;
  const int bb = wv >> 2;
  const int n0 = (wv & 3) * 32;
  const unsigned short* imgp = (const unsigned short*)(ws + IMG_OFF);
  const unsigned short* gB0 = imgp + (size_t)(n0 + lrow)*448 + quad*8;
  const unsigned short* gB1 = gB0 + 16*448;
  const unsigned short* tA = t_s + (size_t)(bb*32)*TSTR + quad*8;

  f32x4 a00 = (f32x4){0.f,0.f,0.f,0.f}, a01 = a00, a10 = a00, a11 = a00;
  bf16x8 Bc0 = *(const bf16x8*)(gB0);
  bf16x8 Bc1 = *(const bf16x8*)(gB1);
  #pragma unroll
  for (int ks = 0; ks < 14; ++ks) {
    bf16x8 Bn0, Bn1;
    if (ks < 13) {
      Bn0 = *(const bf16x8*)(gB0 + (ks+1)*32);
      Bn1 = *(const bf16x8*)(gB1 + (ks+1)*32);
    }
    bf16x8 A0 = *(const bf16x8*)(tA + lrow*TSTR + ks*32);
    bf16x8 A1 = *(const bf16x8*)(tA + (16+lrow)*TSTR + ks*32);
    a00 = __builtin_amdgcn_mfma_f32_16x16x32_bf16(A0, Bc0, a00, 0, 0, 0);
    a01 = __builtin_amdgcn_mfma_f32_16x16x32_bf16(A0, Bc1, a01, 0, 0, 0);
    a10 = __builtin_amdgcn_mfma_f32_16x16x32_bf16(A1, Bc0, a10, 0, 0, 0);
    a11 = __builtin_amdgcn_mfma_f32_16x16x32_bf16(A1, Bc1, a11, 0, 0, 0);
    Bc0 = Bn0; Bc1 = Bn1;
  }
  __syncthreads();   /* all t_s reads done; safe to alias as utile */

  /* utile: per-b [f:128][m:32] stride 34, aliasing t_s */
  {
    unsigned short* ut = t_s + bb*4352;
    const int fb0 = n0 + lrow, fb1 = n0 + 16 + lrow;
    #pragma unroll
    for (int i = 0; i < 4; ++i) {
      int m0 = quad*4 + i, m1 = 16 + quad*4 + i;
      ut[fb0*UTILS + m0] = f2bf(a00[i]);
      ut[fb1*UTILS + m0] = f2bf(a01[i]);
      ut[fb0*UTILS + m1] = f2bf(a10[i]);
      ut[fb1*UTILS + m1] = f2bf(a11[i]);
    }
  }
  __syncthreads();
  {
    const unsigned* u32t = (const unsigned*)t_s;
    unsigned short* ws16 = (unsigned short*)ws;
    #pragma unroll
    for (int it = 0; it < 8; ++it) {
      int idx = tid + it*512;               /* 0..4095 dwords */
      int bbs = idx >> 11, rem = idx & 2047;
      int f = rem >> 4, pr = rem & 15;
      unsigned* Ug = (unsigned*)(ws16 + (size_t)(b0 + bbs)*UTSTR);
      Ug[f*16 + pr] = u32t[bbs*2176 + f*17 + pr];
    }
  }
}

/* K2: finalize bn1 */
__global__ void k2_bn1(float* __restrict__ ws) {
  const int k = threadIdx.x; /* 32 */
  if (k < 29) {
    float s1 = 0.f, s2 = 0.f;
    for (int s = 0; s < 32; ++s) {
      s1 += ws[BN1_OFF + s*58 + k*2 + 0];
      s2 += ws[BN1_OFF + s*58 + k*2 + 1];
    }
    const float inv = 1.f / (float)(B_ * DC);
    float mean = s1 * inv;
    float var  = s2 * inv - mean * mean;
    ws[M1_OFF  + k] = mean;
    ws[IS1_OFF + k] = rsqrtf(var + EPSBN);
  }
}

/* K3: y1 = prelu(corr@bn1(t)@Wg + bg); rowstats {S1,S2,Sv}; bn2 stats. */
__global__ __launch_bounds__(256) void k3_gnn(
    const float* __restrict__ corr, const float* __restrict__ bg,
    const float* __restrict__ agnn, float* __restrict__ ws)
{
  __shared__ float cwf[841];
  __shared__ unsigned short a_s[32*40];
  __shared__ float m1s[29], is1s[29], cms[29], st1s[29], st2s[29], svs[29];

  const int b = blockIdx.x, tid = threadIdx.x;
  const int wv = tid >> 6, lane = tid & 63;
  const int lrow = lane & 15, quad = lane >> 4;
  unsigned short* Utb = (unsigned short*)ws + (size_t)b * UTSTR;

  if (tid < 29) {
    m1s[tid] = ws[M1_OFF+tid]; is1s[tid] = ws[IS1_OFF+tid];
    st1s[tid] = 0.f; st2s[tid] = 0.f; svs[tid] = 0.f;
  }
  const float* cb = corr + (size_t)b * 841;
  for (int i = tid; i < 841; i += 256) cwf[i] = cb[i];
  __syncthreads();

  const int f0 = wv * 32;
  bf16x8 B0 = *(const bf16x8*)&Utb[(f0      + lrow)*32 + quad*8];
  bf16x8 B1 = *(const bf16x8*)&Utb[(f0 + 16 + lrow)*32 + quad*8];

  for (int i = tid; i < 1024; i += 256) {
    int n = i >> 5, m = i & 31;
    float v = (n < 29 && m < 29) ? cwf[n*29 + m] * is1s[m] : 0.f;
    a_s[n*40 + m] = f2bf(v);
  }
  if (tid < 29) {
    float cm = 0.f;
    for (int m = 0; m < 29; ++m) cm = fmaf(cwf[tid*29 + m] * is1s[m], m1s[m], cm);
    cms[tid] = cm;
  }
  __syncthreads();

  bf16x8 A0 = *(const bf16x8*)&a_s[lrow*40 + quad*8];
  bf16x8 A1 = *(const bf16x8*)&a_s[(16 + lrow)*40 + quad*8];
  f32x4 acc[2][2];
  acc[0][0] = (f32x4){0.f,0.f,0.f,0.f}; acc[0][1] = (f32x4){0.f,0.f,0.f,0.f};
  acc[1][0] = (f32x4){0.f,0.f,0.f,0.f}; acc[1][1] = (f32x4){0.f,0.f,0.f,0.f};
  acc[0][0] = __builtin_amdgcn_mfma_f32_16x16x32_bf16(A0, B0, acc[0][0], 0, 0, 0);
  acc[0][1] = __builtin_amdgcn_mfma_f32_16x16x32_bf16(A0, B1, acc[0][1], 0, 0, 0);
  acc[1][0] = __builtin_amdgcn_mfma_f32_16x16x32_bf16(A1, B0, acc[1][0], 0, 0, 0);
  acc[1][1] = __builtin_amdgcn_mfma_f32_16x16x32_bf16(A1, B1, acc[1][1], 0, 0, 0);
  __syncthreads();   /* all waves' Ut reads done -> in-place writes safe */

  const float ag = agnn[0];
  const float vA  = ws[V_OFF  + f0 + lrow],      vB  = ws[V_OFF  + f0 + 16 + lrow];
  const float csA = ws[CSW_OFF + f0 + lrow],     csB = ws[CSW_OFF + f0 + 16 + lrow];
  const float bgA = bg[f0 + lrow],               bgB = bg[f0 + 16 + lrow];
  #pragma unroll
  for (int mt = 0; mt < 2; ++mt) {
    #pragma unroll
    for (int i = 0; i < 4; ++i) {
      int n = mt*16 + quad*4 + i;
      if (n < 29) {
        float y0 = acc[mt][0][i] - cms[n]*csA + bgA;
        float y1 = acc[mt][1][i] - cms[n]*csB + bgB;
        y0 = (y0 >= 0.f) ? y0 : ag*y0;
        y1 = (y1 >= 0.f) ? y1 : ag*y1;
        Utb[n*D_ + f0 + lrow]      = f2bf(y0);
        Utb[n*D_ + f0 + 16 + lrow] = f2bf(y1);
        float sy  = y0 + y1;
        float sy2 = fmaf(y0, y0, y1*y1);
        float sv  = fmaf(y0, vA, y1*vB);
        #pragma unroll
        for (int off = 8; off >= 1; off >>= 1) {
          sy  += __shfl_xor(sy, off);
          sy2 += __shfl_xor(sy2, off);
          sv  += __shfl_xor(sv, off);
        }
        if (lrow == 0) {
          atomicAdd(&st1s[n], sy);
          atomicAdd(&st2s[n], sy2);
          atomicAdd(&svs[n],  sv);
        }
      }
    }
  }
  __syncthreads();
  if (tid < 29) {
    float* rs = (float*)(Utb + RS_SH);
    rs[tid]      = st1s[tid];
    rs[29 + tid] = st2s[tid];
    rs[58 + tid] = svs[tid];
    float* bn2 = ws + BN2_OFF + (size_t)(b & 31) * 58;
    atomicAdd(&bn2[tid*2+0], st1s[tid]);
    atomicAdd(&bn2[tid*2+1], st2s[tid]);
  }
}

__global__ void k3_finalize2(float* __restrict__ ws) {
  const int n = threadIdx.x; /* 32 */
  if (n < 29) {
    float s1 = 0.f, s2 = 0.f;
    for (int s = 0; s < 32; ++s) {
      s1 += ws[BN2_OFF + s*58 + n*2 + 0];
      s2 += ws[BN2_OFF + s*58 + n*2 + 1];
    }
    const float inv = 1.f / (float)(B_ * D_);
    float mean = s1 * inv, var = s2 * inv - mean * mean;
    ws[M2_OFF + n] = mean;
    ws[IS2_OFF + n] = rsqrtf(var + EPSBN);
  }
}

/* K4: rowstats -> softmax weights -> pooled -> @Wp + bp -> x3, bn3. 4 b per block. */
__global__ __launch_bounds__(256) void k4_pool(
    const float* __restrict__ Wp, const float* __restrict__ bpv,
    float* __restrict__ ws)
{
  __shared__ float cs_s[4*32];
  __shared__ float pool_s[4*128];
  const int tid = threadIdx.x, wv = tid >> 6, lane = tid & 63;
  const int b = blockIdx.x * 4 + wv;
  const unsigned short* yb = (const unsigned short*)ws + (size_t)b * UTSTR;
  const float* rs = (const float*)(yb + RS_SH);
  const float V1 = ws[V1_OFF];

  float agg = -1e30f, m2 = 0.f, is2 = 0.f;
  if (lane < 29) {
    float S1 = rs[lane], S2 = rs[29+lane], Sv = rs[58+lane];
    m2 = ws[M2_OFF + lane]; is2 = ws[IS2_OFF + lane];
    float ss = fmaxf(S2 - 2.f*m2*S1 + 128.f*m2*m2, 0.f);
    float rn = sqrtf(ss);
    agg = (is2*(Sv - m2*V1)) / (is2*rn + 1e-8f);
  }
  float mx = agg;
  #pragma unroll
  for (int off = 32; off >= 1; off >>= 1) mx = fmaxf(mx, __shfl_xor(mx, off));
  float e = (lane < 29) ? __expf(agg - mx) : 0.f;
  float den = e, kof = e*is2*m2;
  #pragma unroll
  for (int off = 32; off >= 1; off >>= 1) { den += __shfl_xor(den, off); kof += __shfl_xor(kof, off); }
  float rden = 1.f / den;
  float koff = kof * rden;
  if (lane < 32) cs_s[wv*32 + lane] = (lane < 29) ? e*is2*rden : 0.f;
  __syncthreads();

  const unsigned* y32 = (const unsigned*)yb;
  float p0 = -koff, p1 = -koff;
  #pragma unroll
  for (int n = 0; n < 29; ++n) {
    float c = cs_s[wv*32 + n];
    unsigned u = y32[n*64 + lane];
    p0 = fmaf(c, bf2f(u & 0xffffu), p0);
    p1 = fmaf(c, bf2f(u >> 16), p1);
  }
  pool_s[wv*128 + 2*lane]     = p0;
  pool_s[wv*128 + 2*lane + 1] = p1;
  __syncthreads();

  float a0 = bpv[lane], a1 = bpv[64 + lane];
  const float* ps = pool_s + wv*128;
  #pragma unroll 4
  for (int j = 0; j < 128; ++j) {
    float p = ps[j];
    a0 = fmaf(p, Wp[j*D_ + lane], a0);
    a1 = fmaf(p, Wp[j*D_ + 64 + lane], a1);
  }
  ws[X3_OFF + (size_t)b*D_ + lane]      = a0;
  ws[X3_OFF + (size_t)b*D_ + 64 + lane] = a1;
  float* bn3 = ws + BN3_OFF + (size_t)(b & 31) * 256;
  atomicAdd(&bn3[lane*2+0], a0);
  atomicAdd(&bn3[lane*2+1], a0*a0);
  atomicAdd(&bn3[(64+lane)*2+0], a1);
  atomicAdd(&bn3[(64+lane)*2+1], a1*a1);
}

__global__ void k4_finalize3(float* __restrict__ ws) {
  const int k = threadIdx.x; /* 128 */
  float s1 = 0.f, s2 = 0.f;
  for (int s = 0; s < 32; ++s) {
    s1 += ws[BN3_OFF + s*256 + k*2 + 0];
    s2 += ws[BN3_OFF + s*256 + k*2 + 1];
  }
  const float inv = 1.f / (float)B_;
  float mean = s1 * inv, var = s2 * inv - mean * mean;
  ws[M3_OFF + k] = mean;
  ws[IS3_OFF + k] = rsqrtf(var + EPSBN);
}

/* K5: 4 b per block; one Wm1 sweep feeds 4 accumulators. */
__global__ __launch_bounds__(128) void k5_mlp(
    const float* __restrict__ Wm1, const float* __restrict__ bm1,
    const float* __restrict__ amlp, const float* __restrict__ Wm2,
    const float* __restrict__ bm2, const float* __restrict__ ws,
    float* __restrict__ out)
{
  __shared__ float x_s[4*128];
  __shared__ float red[4][2];
  const int b0 = blockIdx.x * 4, k = threadIdx.x;
  const float m3 = ws[M3_OFF + k], is3 = ws[IS3_OFF + k];
  #pragma unroll
  for (int bb = 0; bb < 4; ++bb)
    x_s[bb*128 + k] = (ws[X3_OFF + (size_t)(b0+bb)*D_ + k] - m3) * is3;
  __syncthreads();
  float h0 = bm1[k], h1 = h0, h2 = h0, h3 = h0;
  #pragma unroll 4
  for (int j = 0; j < 128; ++j) {
    float w = Wm1[j*D_ + k];
    h0 = fmaf(x_s[j],       w, h0);
    h1 = fmaf(x_s[128 + j], w, h1);
    h2 = fmaf(x_s[256 + j], w, h2);
    h3 = fmaf(x_s[384 + j], w, h3);
  }
  const float am = amlp[0];
  const float w2 = Wm2[k];
  h0 = ((h0 >= 0.f) ? h0 : am*h0) * w2;
  h1 = ((h1 >= 0.f) ? h1 : am*h1) * w2;
  h2 = ((h2 >= 0.f) ? h2 : am*h2) * w2;
  h3 = ((h3 >= 0.f) ? h3 : am*h3) * w2;
  #pragma unroll
  for (int off = 32; off >= 1; off >>= 1) {
    h0 += __shfl_down(h0, off);
    h1 += __shfl_down(h1, off);
    h2 += __shfl_down(h2, off);
    h3 += __shfl_down(h3, off);
  }
  if ((k & 63) == 0) {
    int w = k >> 6;
    red[0][w] = h0; red[1][w] = h1; red[2][w] = h2; red[3][w] = h3;
  }
  __syncthreads();
  if (k < 4) {
    float logit = red[k][0] + red[k][1] + bm2[0];
    out[b0 + k] = 1.f / (1.f + expf(-logit));
  }
}

extern "C" void kernel_launch(void* const* d_in, const int* in_sizes, int n_in,
                              void* d_out, int out_size, void* d_ws, size_t ws_size,
                              hipStream_t stream)
{
  (void)in_sizes; (void)n_in; (void)out_size; (void)ws_size;
  const float* X    = (const float*)d_in[0];
  const float* corr = (const float*)d_in[1];
  const float* wc1  = (const float*)d_in[2];
  const float* bc1  = (const float*)d_in[3];
  const float* wc2  = (const float*)d_in[4];
  const float* bc2  = (const float*)d_in[5];
  const float* wc3  = (const float*)d_in[6];
  const float* bc3  = (const float*)d_in[7];
  const float* acnn = (const float*)d_in[8];
  const float* Wg   = (const float*)d_in[9];
  const float* bg   = (const float*)d_in[10];
  const float* agnn = (const float*)d_in[11];
  const float* cent = (const float*)d_in[12];
  const float* hw   = (const float*)d_in[13];
  const float* Wp   = (const float*)d_in[14];
  const float* bp   = (const float*)d_in[15];
  const float* Wm1  = (const float*)d_in[16];
  const float* bm1  = (const float*)d_in[17];
  const float* amlp = (const float*)d_in[18];
  const float* Wm2  = (const float*)d_in[19];
  const float* bm2  = (const float*)d_in[20];
  float* ws  = (float*)d_ws;
  float* out = (float*)d_out;

  hipMemsetAsync(ws + ACC_OFF, 0, 11904 * sizeof(float), stream);
  k0a_img<<<16, 256, 0, stream>>>(Wg, ws);
  k0b_cent<<<1, 128, 0, stream>>>(cent, hw, ws);
  k1_conv_gemm<<<B_/2, 512, 0, stream>>>(X, wc1, bc1, wc2, bc2, wc3, bc3, acnn, ws);
  k2_bn1<<<1, 32, 0, stream>>>(ws);
  k3_gnn<<<B_, 256, 0, stream>>>(corr, bg, agnn, ws);
  k3_finalize2<<<1, 32, 0, stream>>>(ws);
  k4_pool<<<B_/4, 256, 0, stream>>>(Wp, bp, ws);
  k4_finalize3<<<1, 128, 0, stream>>>(ws);
  k5_mlp<<<B_/4, 128, 0, stream>>>(Wm1, bm1, amlp, Wm2, bm2, ws, out);
}

// Round 6
// 479.514 us; speedup vs baseline: 2.0621x; 1.0274x over previous
//
#include <hip/hip_runtime.h>

#define B_    8192
#define N_    29
#define F_    147
#define DC    429
#define D_    128
#define ROWS  (B_*N_)
#define EPSBN 1e-5f

#define UTSTR   4096                        /* shorts per b */
#define RS_SH   3712                        /* short offset of rowstats */

/* ws layout in float units */
#define X3_OFF   16777216                   /* fp32 B_*128 */
#define ACC_OFF  (X3_OFF + B_*D_)
#define BN1_OFF  (ACC_OFF)                  /* 32*29*2 */
#define BN2_OFF  (ACC_OFF + 1856)
#define BN3_OFF  (ACC_OFF + 3712)           /* 32*128*2 */
#define FIN_OFF  (ACC_OFF + 11904)
#define CSW_OFF  (FIN_OFF + 384)
#define V_OFF    (FIN_OFF + 512)
#define V1_OFF   (FIN_OFF + 640)
#define CSWP_OFF (FIN_OFF + 768)
#define IMG_OFF  (FIN_OFF + 1024)           /* bf16 Wg image: 128*448 shorts */
#define WPI_OFF  (IMG_OFF + 28672)          /* bf16 Wp^T image: 128*128 shorts */
#define WM1I_OFF (WPI_OFF + 8192)           /* bf16 Wm1^T image */

typedef __bf16 bf16x8 __attribute__((ext_vector_type(8)));
typedef float  f32x4  __attribute__((ext_vector_type(4)));

__device__ __forceinline__ unsigned short f2bf(float f) {
  unsigned int u = __float_as_uint(f);
  u += 0x7fffu + ((u >> 16) & 1u);
  return (unsigned short)(u >> 16);
}
__device__ __forceinline__ float bf2f(unsigned u16) {
  return __uint_as_float(u16 << 16);
}

#define TSTR 456
#define UTILS 34
#define ATSTR 136   /* k4/k5 A-tile stride (shorts) */

/* K0a: Wg image + colsum (blocks 0..15); Wp^T image + colsum (16); Wm1^T image (17). */
__global__ void k0a_img(const float* __restrict__ Wg, const float* __restrict__ Wp,
                        const float* __restrict__ Wm1, float* __restrict__ ws)
{
  const int tid = threadIdx.x;
  if (blockIdx.x < 16) {
    __shared__ float cs_l[8];
    const int kb = blockIdx.x * 8;
    if (tid < 8) cs_l[tid] = 0.f;
    __syncthreads();
    unsigned short* img = (unsigned short*)(ws + IMG_OFF);
    for (int i = tid; i < 8*448; i += 256) {
      int kk = i / 448, dk = i - kk*448;
      int k = kb + kk;
      int d;
      if      (dk < 145)  d = dk;
      else if (dk == 145) d = -1;
      else if (dk < 289)  d = dk - 1;
      else if (dk == 289) d = -1;
      else if (dk < 431)  d = dk - 2;
      else                d = -1;
      float v = (d >= 0) ? Wg[(size_t)d*D_ + k] : 0.f;
      img[(size_t)k*448 + dk] = f2bf(v);
      if (d >= 0) atomicAdd(&cs_l[kk], v);
    }
    __syncthreads();
    if (tid < 8) ws[CSW_OFF + kb + tid] = cs_l[tid];
  } else if (blockIdx.x == 16) {
    unsigned short* wpi = (unsigned short*)(ws + WPI_OFF);
    for (int i = tid; i < 16384; i += 256) {
      int k = i >> 7, c = i & 127;
      wpi[c*128 + k] = f2bf(Wp[k*128 + c]);
    }
    if (tid < 128) {
      float s = 0.f;
      for (int k = 0; k < 128; ++k) s += Wp[k*128 + tid];
      ws[CSWP_OFF + tid] = s;
    }
  } else {
    unsigned short* wmi = (unsigned short*)(ws + WM1I_OFF);
    for (int i = tid; i < 16384; i += 256) {
      int k = i >> 7, c = i & 127;
      wmi[c*128 + k] = f2bf(Wm1[k*128 + c]);
    }
  }
}

/* K0b: v = sum_h hw[h]*normalize(cent[h]); V1 = sum(v). */
__global__ void k0b_cent(const float* __restrict__ cent, const float* __restrict__ hw,
                         float* __restrict__ ws)
{
  __shared__ float sq[128];
  __shared__ float nrm;
  const int tid = threadIdx.x;
  float vk = 0.f;
  for (int h = 0; h < 4; ++h) {
    float c = cent[h*D_ + tid];
    sq[tid] = c*c;
    __syncthreads();
    if (tid == 0) { float s=0.f; for (int j=0;j<128;++j) s+=sq[j]; nrm = sqrtf(s)+1e-8f; }
    __syncthreads();
    vk += hw[h] * c / nrm;
    __syncthreads();
  }
  ws[V_OFF + tid] = vk;
  sq[tid] = vk;
  __syncthreads();
  if (tid == 0) { float s=0.f; for (int j=0;j<128;++j) s+=sq[j]; ws[V1_OFF] = s; }
}

/* K1: 2 b per block. Conv: 25 X floats preloaded to registers (one latency),
   fully unrolled static-index conv -> ds_write_b16. MFMA phase as r5. */
__global__ __launch_bounds__(512, 2) void k1_conv_gemm(
    const float* __restrict__ X,
    const float* __restrict__ wc1, const float* __restrict__ bc1,
    const float* __restrict__ wc2, const float* __restrict__ bc2,
    const float* __restrict__ wc3, const float* __restrict__ bc3,
    const float* __restrict__ acnn, float* __restrict__ ws)
{
  __shared__ __align__(16) unsigned short t_s[64*TSTR];
  const int tid = threadIdx.x;
  const int b0 = blockIdx.x * 2;

  for (int i = tid; i < 2*3*448; i += 512) {
    int bbz = i / (3*448), rem = i - bbz*(3*448);
    int r = rem / 448, c = rem - r*448;
    t_s[(bbz*32 + 29 + r)*TSTR + c] = 0;
  }
  for (int i = tid; i < 58*19; i += 512) {
    int rr = i / 19, j = i - rr*19;
    int bbz = (rr >= 29), n = rr - bbz*29;
    int col = (j == 0) ? 145 : ((j == 1) ? 289 : (429 + j));
    t_s[(bbz*32 + n)*TSTR + col] = 0;
  }

  const float c10 = wc1[0], c11 = wc1[1], c12 = wc1[2], b1 = bc1[0];
  const float c20 = wc2[0], c21 = wc2[1], c22 = wc2[2], c23 = wc2[3], c24 = wc2[4], b2 = bc2[0];
  const float c30 = wc3[0], c31 = wc3[1], c32 = wc3[2], c33 = wc3[3], c34 = wc3[4],
              c35 = wc3[5], c36 = wc3[6], b3 = bc3[0];
  const float ap = acnn[0];

  {
    const int r = tid >> 3, q = tid & 7;
    const int bb = r >> 5, n = r & 31;
    const bool act = (n < 29);
    const int f0 = q * 19;
    const int nld = act ? n : 28;
    const float* xr = X + (size_t)((b0 + bb)*N_ + nld) * F_;
    float xv[25];
    #pragma unroll
    for (int i = 0; i < 25; ++i) xv[i] = xr[min(f0 + i, 146)];

    float s1 = 0.f, s2 = 0.f;
    unsigned short* tr = t_s + (bb*32 + n)*TSTR;
    if (act) {
      if (q < 7) {
        #pragma unroll
        for (int i = 0; i < 19; ++i) {
          float v1 = fmaf(xv[i],c10, fmaf(xv[i+1],c11, fmaf(xv[i+2],c12, b1)));
          v1 = (v1 >= 0.f) ? v1 : ap*v1;
          s1 += v1; s2 = fmaf(v1, v1, s2);
          tr[f0 + i] = f2bf(v1);
          float v2 = fmaf(xv[i],c20, fmaf(xv[i+1],c21, fmaf(xv[i+2],c22, fmaf(xv[i+3],c23, fmaf(xv[i+4],c24, b2)))));
          v2 = (v2 >= 0.f) ? v2 : ap*v2;
          s1 += v2; s2 = fmaf(v2, v2, s2);
          tr[146 + f0 + i] = f2bf(v2);
          float v3 = fmaf(xv[i],c30, fmaf(xv[i+1],c31, fmaf(xv[i+2],c32, fmaf(xv[i+3],c33, fmaf(xv[i+4],c34, fmaf(xv[i+5],c35, fmaf(xv[i+6],c36, b3)))))));
          v3 = (v3 >= 0.f) ? v3 : ap*v3;
          s1 += v3; s2 = fmaf(v3, v3, s2);
          tr[290 + f0 + i] = f2bf(v3);
        }
      } else {   /* q==7: f0==133, constant trips */
        #pragma unroll
        for (int i = 0; i < 12; ++i) {
          float v1 = fmaf(xv[i],c10, fmaf(xv[i+1],c11, fmaf(xv[i+2],c12, b1)));
          v1 = (v1 >= 0.f) ? v1 : ap*v1;
          s1 += v1; s2 = fmaf(v1, v1, s2);
          tr[133 + i] = f2bf(v1);
        }
        #pragma unroll
        for (int i = 0; i < 10; ++i) {
          float v2 = fmaf(xv[i],c20, fmaf(xv[i+1],c21, fmaf(xv[i+2],c22, fmaf(xv[i+3],c23, fmaf(xv[i+4],c24, b2)))));
          v2 = (v2 >= 0.f) ? v2 : ap*v2;
          s1 += v2; s2 = fmaf(v2, v2, s2);
          tr[279 + i] = f2bf(v2);
        }
        #pragma unroll
        for (int i = 0; i < 8; ++i) {
          float v3 = fmaf(xv[i],c30, fmaf(xv[i+1],c31, fmaf(xv[i+2],c32, fmaf(xv[i+3],c33, fmaf(xv[i+4],c34, fmaf(xv[i+5],c35, fmaf(xv[i+6],c36, b3)))))));
          v3 = (v3 >= 0.f) ? v3 : ap*v3;
          s1 += v3; s2 = fmaf(v3, v3, s2);
          tr[423 + i] = f2bf(v3);
        }
      }
    }
    #pragma unroll
    for (int off = 4; off >= 1; off >>= 1) {
      s1 += __shfl_xor(s1, off);
      s2 += __shfl_xor(s2, off);
    }
    if (act && q == 0) {
      float* bn1 = ws + BN1_OFF + (size_t)(blockIdx.x & 31) * 58;
      atomicAdd(&bn1[n*2+0], s1);
      atomicAdd(&bn1[n*2+1], s2);
    }
  }
  __syncthreads();

  const int wv = tid >> 6, lane = tid & 63;
  const int lrow = lane & 15, quad = lane >> 4;
  const int bb = wv >> 2;
  const int n0 = (wv & 3) * 32;
  const unsigned short* imgp = (const unsigned short*)(ws + IMG_OFF);
  const unsigned short* gB0 = imgp + (size_t)(n0 + lrow)*448 + quad*8;
  const unsigned short* gB1 = gB0 + 16*448;
  const unsigned short* tA = t_s + (size_t)(bb*32)*TSTR + quad*8;

  f32x4 a00 = (f32x4){0.f,0.f,0.f,0.f}, a01 = a00, a10 = a00, a11 = a00;
  bf16x8 Bc0 = *(const bf16x8*)(gB0);
  bf16x8 Bc1 = *(const bf16x8*)(gB1);
  #pragma unroll
  for (int ks = 0; ks < 14; ++ks) {
    bf16x8 Bn0, Bn1;
    if (ks < 13) {
      Bn0 = *(const bf16x8*)(gB0 + (ks+1)*32);
      Bn1 = *(const bf16x8*)(gB1 + (ks+1)*32);
    }
    bf16x8 A0 = *(const bf16x8*)(tA + lrow*TSTR + ks*32);
    bf16x8 A1 = *(const bf16x8*)(tA + (16+lrow)*TSTR + ks*32);
    a00 = __builtin_amdgcn_mfma_f32_16x16x32_bf16(A0, Bc0, a00, 0, 0, 0);
    a01 = __builtin_amdgcn_mfma_f32_16x16x32_bf16(A0, Bc1, a01, 0, 0, 0);
    a10 = __builtin_amdgcn_mfma_f32_16x16x32_bf16(A1, Bc0, a10, 0, 0, 0);
    a11 = __builtin_amdgcn_mfma_f32_16x16x32_bf16(A1, Bc1, a11, 0, 0, 0);
    Bc0 = Bn0; Bc1 = Bn1;
  }
  __syncthreads();

  {
    unsigned short* ut = t_s + bb*4352;
    const int fb0 = n0 + lrow, fb1 = n0 + 16 + lrow;
    #pragma unroll
    for (int i = 0; i < 4; ++i) {
      int m0 = quad*4 + i, m1 = 16 + quad*4 + i;
      ut[fb0*UTILS + m0] = f2bf(a00[i]);
      ut[fb1*UTILS + m0] = f2bf(a01[i]);
      ut[fb0*UTILS + m1] = f2bf(a10[i]);
      ut[fb1*UTILS + m1] = f2bf(a11[i]);
    }
  }
  __syncthreads();
  {
    const unsigned* u32t = (const unsigned*)t_s;
    unsigned short* ws16 = (unsigned short*)ws;
    #pragma unroll
    for (int it = 0; it < 8; ++it) {
      int idx = tid + it*512;
      int bbs = idx >> 11, rem = idx & 2047;
      int f = rem >> 4, pr = rem & 15;
      unsigned* Ug = (unsigned*)(ws16 + (size_t)(b0 + bbs)*UTSTR);
      Ug[f*16 + pr] = u32t[bbs*2176 + f*17 + pr];
    }
  }
}

/* K3: bn1 finalize in-block; y1 = prelu(corr@bn1(t)@Wg + bg); rowstats; bn2 stats. */
__global__ __launch_bounds__(256) void k3_gnn(
    const float* __restrict__ corr, const float* __restrict__ bg,
    const float* __restrict__ agnn, float* __restrict__ ws)
{
  __shared__ float cwf[841];
  __shared__ unsigned short a_s[32*40];
  __shared__ float m1s[29], is1s[29], cms[29], st1s[29], st2s[29], svs[29];

  const int b = blockIdx.x, tid = threadIdx.x;
  const int wv = tid >> 6, lane = tid & 63;
  const int lrow = lane & 15, quad = lane >> 4;
  unsigned short* Utb = (unsigned short*)ws + (size_t)b * UTSTR;

  if (tid < 29) {
    float s1 = 0.f, s2 = 0.f;
    #pragma unroll 4
    for (int s = 0; s < 32; ++s) {
      s1 += ws[BN1_OFF + s*58 + tid*2 + 0];
      s2 += ws[BN1_OFF + s*58 + tid*2 + 1];
    }
    const float inv = 1.f / (float)(B_ * DC);
    float mean = s1 * inv;
    float var  = s2 * inv - mean * mean;
    m1s[tid] = mean; is1s[tid] = rsqrtf(var + EPSBN);
    st1s[tid] = 0.f; st2s[tid] = 0.f; svs[tid] = 0.f;
  }
  const float* cb = corr + (size_t)b * 841;
  for (int i = tid; i < 841; i += 256) cwf[i] = cb[i];
  __syncthreads();

  const int f0 = wv * 32;
  bf16x8 B0 = *(const bf16x8*)&Utb[(f0      + lrow)*32 + quad*8];
  bf16x8 B1 = *(const bf16x8*)&Utb[(f0 + 16 + lrow)*32 + quad*8];

  for (int i = tid; i < 1024; i += 256) {
    int n = i >> 5, m = i & 31;
    float v = (n < 29 && m < 29) ? cwf[n*29 + m] * is1s[m] : 0.f;
    a_s[n*40 + m] = f2bf(v);
  }
  if (tid < 29) {
    float cm = 0.f;
    for (int m = 0; m < 29; ++m) cm = fmaf(cwf[tid*29 + m] * is1s[m], m1s[m], cm);
    cms[tid] = cm;
  }
  __syncthreads();

  bf16x8 A0 = *(const bf16x8*)&a_s[lrow*40 + quad*8];
  bf16x8 A1 = *(const bf16x8*)&a_s[(16 + lrow)*40 + quad*8];
  f32x4 acc[2][2];
  acc[0][0] = (f32x4){0.f,0.f,0.f,0.f}; acc[0][1] = (f32x4){0.f,0.f,0.f,0.f};
  acc[1][0] = (f32x4){0.f,0.f,0.f,0.f}; acc[1][1] = (f32x4){0.f,0.f,0.f,0.f};
  acc[0][0] = __builtin_amdgcn_mfma_f32_16x16x32_bf16(A0, B0, acc[0][0], 0, 0, 0);
  acc[0][1] = __builtin_amdgcn_mfma_f32_16x16x32_bf16(A0, B1, acc[0][1], 0, 0, 0);
  acc[1][0] = __builtin_amdgcn_mfma_f32_16x16x32_bf16(A1, B0, acc[1][0], 0, 0, 0);
  acc[1][1] = __builtin_amdgcn_mfma_f32_16x16x32_bf16(A1, B1, acc[1][1], 0, 0, 0);
  __syncthreads();

  const float ag = agnn[0];
  const float vA  = ws[V_OFF  + f0 + lrow],      vB  = ws[V_OFF  + f0 + 16 + lrow];
  const float csA = ws[CSW_OFF + f0 + lrow],     csB = ws[CSW_OFF + f0 + 16 + lrow];
  const float bgA = bg[f0 + lrow],               bgB = bg[f0 + 16 + lrow];
  #pragma unroll
  for (int mt = 0; mt < 2; ++mt) {
    #pragma unroll
    for (int i = 0; i < 4; ++i) {
      int n = mt*16 + quad*4 + i;
      if (n < 29) {
        float y0 = acc[mt][0][i] - cms[n]*csA + bgA;
        float y1 = acc[mt][1][i] - cms[n]*csB + bgB;
        y0 = (y0 >= 0.f) ? y0 : ag*y0;
        y1 = (y1 >= 0.f) ? y1 : ag*y1;
        Utb[n*D_ + f0 + lrow]      = f2bf(y0);
        Utb[n*D_ + f0 + 16 + lrow] = f2bf(y1);
        float sy  = y0 + y1;
        float sy2 = fmaf(y0, y0, y1*y1);
        float sv  = fmaf(y0, vA, y1*vB);
        #pragma unroll
        for (int off = 8; off >= 1; off >>= 1) {
          sy  += __shfl_xor(sy, off);
          sy2 += __shfl_xor(sy2, off);
          sv  += __shfl_xor(sv, off);
        }
        if (lrow == 0) {
          atomicAdd(&st1s[n], sy);
          atomicAdd(&st2s[n], sy2);
          atomicAdd(&svs[n],  sv);
        }
      }
    }
  }
  __syncthreads();
  if (tid < 29) {
    float* rs = (float*)(Utb + RS_SH);
    rs[tid]      = st1s[tid];
    rs[29 + tid] = st2s[tid];
    rs[58 + tid] = svs[tid];
    float* bn2 = ws + BN2_OFF + (size_t)(b & 31) * 58;
    atomicAdd(&bn2[tid*2+0], st1s[tid]);
    atomicAdd(&bn2[tid*2+1], st2s[tid]);
  }
}

/* K4: 32 b per block. bn2 finalize in-block; pooling -> bf16 A-tile;
   x3 = A @ Wp^T (MFMA) - koff*cswp + bp; bn3 stats. */
__global__ __launch_bounds__(256) void k4_pool(
    const float* __restrict__ bpv, float* __restrict__ ws)
{
  __shared__ unsigned short Atile[32*ATSTR];   /* 8704 B */
  __shared__ float m2s[29], is2s[29], koffs[32];
  const int tid = threadIdx.x, wv = tid >> 6, lane = tid & 63;
  const int b0 = blockIdx.x * 32;
  const unsigned short* U16 = (const unsigned short*)ws;

  if (tid < 29) {
    float s1 = 0.f, s2 = 0.f;
    #pragma unroll 4
    for (int s = 0; s < 32; ++s) {
      s1 += ws[BN2_OFF + s*58 + tid*2 + 0];
      s2 += ws[BN2_OFF + s*58 + tid*2 + 1];
    }
    const float inv = 1.f / (float)(B_ * D_);
    float mean = s1 * inv, var = s2 * inv - mean * mean;
    m2s[tid] = mean; is2s[tid] = rsqrtf(var + EPSBN);
  }
  __syncthreads();

  const float V1 = ws[V1_OFF];
  unsigned* At32 = (unsigned*)Atile;
  for (int mb = 0; mb < 8; ++mb) {
    const int m = wv*8 + mb;
    const unsigned short* yb = U16 + (size_t)(b0 + m) * UTSTR;
    const float* rs = (const float*)(yb + RS_SH);
    float agg = -1e30f, m2 = 0.f, is2 = 0.f;
    if (lane < 29) {
      float S1 = rs[lane], S2 = rs[29+lane], Sv = rs[58+lane];
      m2 = m2s[lane]; is2 = is2s[lane];
      float ss = fmaxf(S2 - 2.f*m2*S1 + 128.f*m2*m2, 0.f);
      agg = (is2*(Sv - m2*V1)) / (is2*sqrtf(ss) + 1e-8f);
    }
    float mx = agg;
    #pragma unroll
    for (int off = 32; off >= 1; off >>= 1) mx = fmaxf(mx, __shfl_xor(mx, off));
    float e = (lane < 29) ? __expf(agg - mx) : 0.f;
    float den = e, kof = e*is2*m2;
    #pragma unroll
    for (int off = 32; off >= 1; off >>= 1) { den += __shfl_xor(den, off); kof += __shfl_xor(kof, off); }
    float rden = 1.f / den;
    float c = e * is2 * rden;
    if (lane == 0) koffs[m] = kof * rden;
    const unsigned* y32 = (const unsigned*)yb;
    float p0 = 0.f, p1 = 0.f;
    #pragma unroll
    for (int n = 0; n < 29; ++n) {
      float cn = __shfl(c, n);
      unsigned u = y32[n*64 + lane];
      p0 = fmaf(cn, bf2f(u & 0xffffu), p0);
      p1 = fmaf(cn, bf2f(u >> 16), p1);
    }
    At32[m*68 + lane] = (unsigned)f2bf(p0) | ((unsigned)f2bf(p1) << 16);
  }
  __syncthreads();

  const int lrow = lane & 15, quad = lane >> 4;
  const int n0 = wv * 32;
  const unsigned short* wpi = (const unsigned short*)(ws + WPI_OFF);
  f32x4 acc[2][2];
  acc[0][0] = (f32x4){0.f,0.f,0.f,0.f}; acc[0][1] = acc[0][0];
  acc[1][0] = acc[0][0]; acc[1][1] = acc[0][0];
  #pragma unroll
  for (int ks = 0; ks < 4; ++ks) {
    bf16x8 A0 = *(const bf16x8*)&Atile[lrow*ATSTR + ks*32 + quad*8];
    bf16x8 A1 = *(const bf16x8*)&Atile[(16+lrow)*ATSTR + ks*32 + quad*8];
    bf16x8 Bq0 = *(const bf16x8*)&wpi[(size_t)(n0 + lrow)*128 + ks*32 + quad*8];
    bf16x8 Bq1 = *(const bf16x8*)&wpi[(size_t)(n0 + 16 + lrow)*128 + ks*32 + quad*8];
    acc[0][0] = __builtin_amdgcn_mfma_f32_16x16x32_bf16(A0, Bq0, acc[0][0], 0, 0, 0);
    acc[0][1] = __builtin_amdgcn_mfma_f32_16x16x32_bf16(A0, Bq1, acc[0][1], 0, 0, 0);
    acc[1][0] = __builtin_amdgcn_mfma_f32_16x16x32_bf16(A1, Bq0, acc[1][0], 0, 0, 0);
    acc[1][1] = __builtin_amdgcn_mfma_f32_16x16x32_bf16(A1, Bq1, acc[1][1], 0, 0, 0);
  }

  float* bn3 = ws + BN3_OFF + (size_t)(blockIdx.x & 31) * 256;
  #pragma unroll
  for (int nt = 0; nt < 2; ++nt) {
    int col = n0 + nt*16 + lrow;
    float cswp = ws[CSWP_OFF + col], bp = bpv[col];
    float s1c = 0.f, s2c = 0.f;
    #pragma unroll
    for (int mt = 0; mt < 2; ++mt) {
      #pragma unroll
      for (int i = 0; i < 4; ++i) {
        int m = mt*16 + quad*4 + i;
        float x3 = acc[mt][nt][i] - koffs[m]*cswp + bp;
        ws[X3_OFF + (size_t)(b0 + m)*D_ + col] = x3;
        s1c += x3; s2c = fmaf(x3, x3, s2c);
      }
    }
    s1c += __shfl_xor(s1c, 16); s1c += __shfl_xor(s1c, 32);
    s2c += __shfl_xor(s2c, 16); s2c += __shfl_xor(s2c, 32);
    if (quad == 0) {
      atomicAdd(&bn3[col*2+0], s1c);
      atomicAdd(&bn3[col*2+1], s2c);
    }
  }
}

/* K5: 32 b per block. bn3 finalize in-block; h = prelu(bn3(x3)@Wm1 + bm1) (MFMA);
   logit = h . Wm2 + bm2 -> sigmoid. */
__global__ __launch_bounds__(256) void k5_mlp(
    const float* __restrict__ bm1, const float* __restrict__ amlp,
    const float* __restrict__ Wm2, const float* __restrict__ bm2,
    float* __restrict__ ws, float* __restrict__ out)
{
  __shared__ unsigned short Atile[32*ATSTR];
  __shared__ float m3s[128], is3s[128], logit_s[32];
  const int tid = threadIdx.x, wv = tid >> 6, lane = tid & 63;
  const int b0 = blockIdx.x * 32;

  if (tid < 128) {
    float s1 = 0.f, s2 = 0.f;
    #pragma unroll 4
    for (int s = 0; s < 32; ++s) {
      s1 += ws[BN3_OFF + s*256 + tid*2 + 0];
      s2 += ws[BN3_OFF + s*256 + tid*2 + 1];
    }
    const float inv = 1.f / (float)B_;
    float mean = s1 * inv, var = s2 * inv - mean * mean;
    m3s[tid] = mean; is3s[tid] = rsqrtf(var + EPSBN);
  }
  if (tid >= 128 && tid < 160) logit_s[tid-128] = 0.f;
  __syncthreads();

  for (int it = 0; it < 16; ++it) {
    int idx = tid + it*256;
    int row = idx >> 7, col = idx & 127;
    float v = (ws[X3_OFF + (size_t)(b0+row)*D_ + col] - m3s[col]) * is3s[col];
    Atile[row*ATSTR + col] = f2bf(v);
  }
  __syncthreads();

  const int lrow = lane & 15, quad = lane >> 4;
  const int n0 = wv * 32;
  const unsigned short* wmi = (const unsigned short*)(ws + WM1I_OFF);
  f32x4 acc[2][2];
  acc[0][0] = (f32x4){0.f,0.f,0.f,0.f}; acc[0][1] = acc[0][0];
  acc[1][0] = acc[0][0]; acc[1][1] = acc[0][0];
  #pragma unroll
  for (int ks = 0; ks < 4; ++ks) {
    bf16x8 A0 = *(const bf16x8*)&Atile[lrow*ATSTR + ks*32 + quad*8];
    bf16x8 A1 = *(const bf16x8*)&Atile[(16+lrow)*ATSTR + ks*32 + quad*8];
    bf16x8 Bq0 = *(const bf16x8*)&wmi[(size_t)(n0 + lrow)*128 + ks*32 + quad*8];
    bf16x8 Bq1 = *(const bf16x8*)&wmi[(size_t)(n0 + 16 + lrow)*128 + ks*32 + quad*8];
    acc[0][0] = __builtin_amdgcn_mfma_f32_16x16x32_bf16(A0, Bq0, acc[0][0], 0, 0, 0);
    acc[0][1] = __builtin_amdgcn_mfma_f32_16x16x32_bf16(A0, Bq1, acc[0][1], 0, 0, 0);
    acc[1][0] = __builtin_amdgcn_mfma_f32_16x16x32_bf16(A1, Bq0, acc[1][0], 0, 0, 0);
    acc[1][1] = __builtin_amdgcn_mfma_f32_16x16x32_bf16(A1, Bq1, acc[1][1], 0, 0, 0);
  }

  const float am = amlp[0];
  float bmc[2], wm2c[2];
  #pragma unroll
  for (int nt = 0; nt < 2; ++nt) {
    int col = n0 + nt*16 + lrow;
    bmc[nt] = bm1[col]; wm2c[nt] = Wm2[col];
  }
  #pragma unroll
  for (int mt = 0; mt < 2; ++mt) {
    #pragma unroll
    for (int i = 0; i < 4; ++i) {
      float pm = 0.f;
      #pragma unroll
      for (int nt = 0; nt < 2; ++nt) {
        float h = acc[mt][nt][i] + bmc[nt];
        h = (h >= 0.f) ? h : am*h;
        pm = fmaf(h, wm2c[nt], pm);
      }
      #pragma unroll
      for (int off = 8; off >= 1; off >>= 1) pm += __shfl_xor(pm, off);
      if (lrow == 0) atomicAdd(&logit_s[mt*16 + quad*4 + i], pm);
    }
  }
  __syncthreads();
  if (tid < 32) {
    float logit = logit_s[tid] + bm2[0];
    out[b0 + tid] = 1.f / (1.f + expf(-logit));
  }
}

extern "C" void kernel_launch(void* const* d_in, const int* in_sizes, int n_in,
                              void* d_out, int out_size, void* d_ws, size_t ws_size,
                              hipStream_t stream)
{
  (void)in_sizes; (void)n_in; (void)out_size; (void)ws_size;
  const float* X    = (const float*)d_in[0];
  const float* corr = (const float*)d_in[1];
  const float* wc1  = (const float*)d_in[2];
  const float* bc1  = (const float*)d_in[3];
  const float* wc2  = (const float*)d_in[4];
  const float* bc2  = (const float*)d_in[5];
  const float* wc3  = (const float*)d_in[6];
  const float* bc3  = (const float*)d_in[7];
  const float* acnn = (const float*)d_in[8];
  const float* Wg   = (const float*)d_in[9];
  const float* bg   = (const float*)d_in[10];
  const float* agnn = (const float*)d_in[11];
  const float* cent = (const float*)d_in[12];
  const float* hw   = (const float*)d_in[13];
  const float* Wp   = (const float*)d_in[14];
  const float* bp   = (const float*)d_in[15];
  const float* Wm1  = (const float*)d_in[16];
  const float* bm1  = (const float*)d_in[17];
  const float* amlp = (const float*)d_in[18];
  const float* Wm2  = (const float*)d_in[19];
  const float* bm2  = (const float*)d_in[20];
  float* ws  = (float*)d_ws;
  float* out = (float*)d_out;

  hipMemsetAsync(ws + ACC_OFF, 0, 11904 * sizeof(float), stream);
  k0a_img<<<18, 256, 0, stream>>>(Wg, Wp, Wm1, ws);
  k0b_cent<<<1, 128, 0, stream>>>(cent, hw, ws);
  k1_conv_gemm<<<B_/2, 512, 0, stream>>>(X, wc1, bc1, wc2, bc2, wc3, bc3, acnn, ws);
  k3_gnn<<<B_, 256, 0, stream>>>(corr, bg, agnn, ws);
  k4_pool<<<B_/32, 256, 0, stream>>>(bp, ws);
  k5_mlp<<<B_/32, 256, 0, stream>>>(bm1, amlp, Wm2, bm2, ws, out);
}